// Round 1
// baseline (721.885 us; speedup 1.0000x reference)
//
#include <hip/hip_runtime.h>

// ---------------------------------------------------------------------------
// ContrastiveGNN: 2-layer GCN + global mean pool + linear head.
//
// Algebraic restructure:
//   hs1[v]   = (x[v] @ W1) * dinv[v]                       (GEMM1, fused scale)
//   g1[v]    = relu(dinv[v]*(hs1[v] + sum_{u->v} hs1[u]) + b1)
//   gs1[v]   = g1[v] * dinv[v]                             (gather1, fused)
//   a2[v]    = dinv[v]*(gs1[v] + sum_{u->v} gs1[u])        (gather2)
//   pool[g]  = mean_{v in g} a2[v]                         (fused atomic pool)
//   emb      = pool @ W2 + b2       (512x128x256 -- tiny, head kernel)
//   logits   = emb @ Wg + bg
// This removes the 100000x256 GEMM + buffer entirely (pooling commutes with
// the linear map; dropout is identity in eval).
//
// Aggregation via device-built dst-CSR (count -> scan -> scatter), gather
// style: 1 wave per node, 64 lanes x float2 = 128-feature row in registers.
// ---------------------------------------------------------------------------

#define TPB 256

__global__ void count_deg(const int* __restrict__ ei, int E, int* __restrict__ deg) {
    int e = blockIdx.x * blockDim.x + threadIdx.x;
    if (e < E) atomicAdd(&deg[ei[E + e]], 1);  // dst = edge_index[1][e]
}

__global__ void dinv_cnt(const int* __restrict__ deg, float* __restrict__ dinv, int n,
                         const int* __restrict__ batch, int* __restrict__ cnt) {
    int v = blockIdx.x * blockDim.x + threadIdx.x;
    if (v < n) {
        dinv[v] = rsqrtf((float)(deg[v] + 1));   // +1 = self loop
        atomicAdd(&cnt[batch[v]], 1);
    }
}

// ---- exclusive scan of deg -> offs (3-kernel, 2048 elems/block) ----
#define SCAN_EPT 8
#define SCAN_EPB (TPB * SCAN_EPT)   // 2048

__global__ void scan1(const int* __restrict__ deg, int n,
                      int* __restrict__ offs, int* __restrict__ bsums) {
    __shared__ int s[TPB];
    int t = threadIdx.x;
    int base = blockIdx.x * SCAN_EPB + t * SCAN_EPT;
    int vals[SCAN_EPT];
    int tot = 0;
#pragma unroll
    for (int i = 0; i < SCAN_EPT; ++i) {
        int idx = base + i;
        int v = (idx < n) ? deg[idx] : 0;
        vals[i] = tot;   // exclusive within thread
        tot += v;
    }
    s[t] = tot;
    __syncthreads();
    for (int off = 1; off < TPB; off <<= 1) {
        int v = (t >= off) ? s[t - off] : 0;
        __syncthreads();
        s[t] += v;
        __syncthreads();
    }
    int excl = s[t] - tot;
#pragma unroll
    for (int i = 0; i < SCAN_EPT; ++i) {
        int idx = base + i;
        if (idx < n) offs[idx] = excl + vals[i];
    }
    if (t == TPB - 1) bsums[blockIdx.x] = s[t];
}

__global__ void scan2(int* __restrict__ bsums, int nb) {
    if (threadIdx.x == 0 && blockIdx.x == 0) {
        int run = 0;
        for (int i = 0; i < nb; ++i) { int v = bsums[i]; bsums[i] = run; run += v; }
    }
}

__global__ void scan3(int* __restrict__ offs, int n, const int* __restrict__ bsums) {
    int i = blockIdx.x * blockDim.x + threadIdx.x;
    if (i < n) offs[i] += bsums[i / SCAN_EPB];
}

__global__ void build_csr(const int* __restrict__ ei, int E, const int* __restrict__ offs,
                          int* __restrict__ cursor, int* __restrict__ adj) {
    int e = blockIdx.x * blockDim.x + threadIdx.x;
    if (e < E) {
        int s = ei[e], d = ei[E + e];
        int pos = offs[d] + atomicAdd(&cursor[d], 1);
        adj[pos] = s;
    }
}

// ---- GEMM1: hs1 = (x @ W1) * dinv[row].  M=n, N=128, K=128, f32 ----
#define BM 64
#define BN 128
#define BK 32
#define TM 4
#define TN 8

__global__ __launch_bounds__(256) void gemm1(const float* __restrict__ X,
                                             const float* __restrict__ W,
                                             const float* __restrict__ dinv,
                                             float* __restrict__ out, int n) {
    __shared__ float As[BK][BM + 1];   // +1 pad: kills 32-way write conflict
    __shared__ float Bs[BK][BN];
    int t = threadIdx.x;
    int tx = t % 16, ty = t / 16;
    int rowBase = blockIdx.x * BM;
    float acc[TM][TN] = {};
    for (int k0 = 0; k0 < 128; k0 += BK) {
#pragma unroll
        for (int i = 0; i < (BM * BK) / 256; ++i) {   // 8
            int e = i * 256 + t;
            int r = e / BK, kk = e % BK;
            int gr = rowBase + r;
            As[kk][r] = (gr < n) ? X[(size_t)gr * 128 + k0 + kk] : 0.f;
        }
#pragma unroll
        for (int i = 0; i < (BK * BN) / 256; ++i) {   // 16
            int e = i * 256 + t;
            int kk = e / BN, c = e % BN;
            Bs[kk][c] = W[(size_t)(k0 + kk) * 128 + c];
        }
        __syncthreads();
#pragma unroll
        for (int kk = 0; kk < BK; ++kk) {
            float a[TM], b[TN];
#pragma unroll
            for (int m = 0; m < TM; ++m) a[m] = As[kk][ty * TM + m];
#pragma unroll
            for (int j = 0; j < TN; ++j) b[j] = Bs[kk][tx * TN + j];
#pragma unroll
            for (int m = 0; m < TM; ++m)
#pragma unroll
                for (int j = 0; j < TN; ++j)
                    acc[m][j] += a[m] * b[j];
        }
        __syncthreads();
    }
#pragma unroll
    for (int m = 0; m < TM; ++m) {
        int gr = rowBase + ty * TM + m;
        if (gr < n) {
            float s = dinv[gr];
#pragma unroll
            for (int j = 0; j < TN; ++j)
                out[(size_t)gr * 128 + tx * TN + j] = acc[m][j] * s;
        }
    }
}

// ---- gather1: g1 = relu(dinv*(self+neighbors)+b1); store gs1 = g1*dinv ----
__global__ void gather1(const float* __restrict__ hs, const int* __restrict__ adj,
                        const int* __restrict__ offs, const int* __restrict__ deg,
                        const float* __restrict__ dinv, const float* __restrict__ b1,
                        float* __restrict__ gs, int n) {
    int wave = threadIdx.x >> 6;
    int lane = threadIdx.x & 63;
    int v = blockIdx.x * 4 + wave;
    if (v >= n) return;
    const float2* self = (const float2*)(hs + (size_t)v * 128);
    float2 acc = self[lane];
    int start = offs[v], d = deg[v];
    for (int i = 0; i < d; ++i) {
        int u = adj[start + i];
        const float2* r = (const float2*)(hs + (size_t)u * 128);
        float2 x = r[lane];
        acc.x += x.x;
        acc.y += x.y;
    }
    float dv = dinv[v];
    float2 bb = ((const float2*)b1)[lane];
    float g0 = fmaxf(acc.x * dv + bb.x, 0.f);
    float g1 = fmaxf(acc.y * dv + bb.y, 0.f);
    float2* o = (float2*)(gs + (size_t)v * 128);
    o[lane] = make_float2(g0 * dv, g1 * dv);
}

// ---- gather2 + fused atomic mean-pool accumulate ----
__global__ void gather2_pool(const float* __restrict__ gs, const int* __restrict__ adj,
                             const int* __restrict__ offs, const int* __restrict__ deg,
                             const float* __restrict__ dinv, const int* __restrict__ batch,
                             float* __restrict__ poolsum, int n) {
    int wave = threadIdx.x >> 6;
    int lane = threadIdx.x & 63;
    int v = blockIdx.x * 4 + wave;
    if (v >= n) return;
    const float2* self = (const float2*)(gs + (size_t)v * 128);
    float2 acc = self[lane];
    int start = offs[v], d = deg[v];
    for (int i = 0; i < d; ++i) {
        int u = adj[start + i];
        const float2* r = (const float2*)(gs + (size_t)u * 128);
        float2 x = r[lane];
        acc.x += x.x;
        acc.y += x.y;
    }
    float dv = dinv[v];
    float* p = poolsum + (size_t)batch[v] * 128;
    atomicAdd(&p[lane * 2 + 0], acc.x * dv);
    atomicAdd(&p[lane * 2 + 1], acc.y * dv);
}

// ---- head: emb = (pool/cnt) @ W2 + b2 ; logits = emb @ Wg + bg ----
__global__ void head(const float* __restrict__ poolsum, const int* __restrict__ cnt,
                     const float* __restrict__ W2, const float* __restrict__ b2,
                     const float* __restrict__ Wg, const float* __restrict__ bg,
                     float* __restrict__ out, int G) {
    __shared__ float pm[128];
    __shared__ float emb[256];
    int g = blockIdx.x, t = threadIdx.x;
    float inv = 1.f / fmaxf((float)cnt[g], 1.f);
    if (t < 128) pm[t] = poolsum[(size_t)g * 128 + t] * inv;
    __syncthreads();
    float acc = b2[t];
    for (int k = 0; k < 128; ++k) acc += pm[k] * W2[k * 256 + t];
    out[(size_t)g * 256 + t] = acc;
    emb[t] = acc;
    __syncthreads();
    if (t < 16) {
        float a = bg[t];
        for (int j = 0; j < 256; ++j) a += emb[j] * Wg[j * 16 + t];
        out[(size_t)G * 256 + g * 16 + t] = a;
    }
}

extern "C" void kernel_launch(void* const* d_in, const int* in_sizes, int n_in,
                              void* d_out, int out_size, void* d_ws, size_t ws_size,
                              hipStream_t stream) {
    const float* x     = (const float*)d_in[0];
    const int*   ei    = (const int*)d_in[1];
    const int*   batch = (const int*)d_in[2];
    const float* W1    = (const float*)d_in[4];
    const float* b1    = (const float*)d_in[5];
    const float* W2    = (const float*)d_in[6];
    const float* b2    = (const float*)d_in[7];
    const float* Wg    = (const float*)d_in[8];
    const float* bg    = (const float*)d_in[9];
    float* out = (float*)d_out;

    int n = in_sizes[0] / 128;
    int E = in_sizes[1] / 2;
    int G = out_size / (256 + 16);

    // workspace carve-out (256B-aligned)
    char* ws = (char*)d_ws;
    auto alloc = [&](size_t bytes) {
        char* p = ws;
        ws += (bytes + 255) & ~(size_t)255;
        return p;
    };
    int*   deg     = (int*)alloc((size_t)n * 4);
    float* dinv    = (float*)alloc((size_t)n * 4);
    int*   offs    = (int*)alloc((size_t)n * 4);
    int*   cursor  = (int*)alloc((size_t)n * 4);
    int*   adj     = (int*)alloc((size_t)E * 4);
    int*   bsums   = (int*)alloc(256 * 4);
    int*   cnt     = (int*)alloc((size_t)G * 4);
    float* poolsum = (float*)alloc((size_t)G * 128 * 4);
    float* hs1     = (float*)alloc((size_t)n * 128 * 4);
    float* gs1     = (float*)alloc((size_t)n * 128 * 4);

    hipMemsetAsync(deg, 0, (size_t)n * 4, stream);
    hipMemsetAsync(cursor, 0, (size_t)n * 4, stream);
    hipMemsetAsync(cnt, 0, (size_t)G * 4, stream);
    hipMemsetAsync(poolsum, 0, (size_t)G * 128 * 4, stream);

    count_deg<<<(E + TPB - 1) / TPB, TPB, 0, stream>>>(ei, E, deg);
    dinv_cnt<<<(n + TPB - 1) / TPB, TPB, 0, stream>>>(deg, dinv, n, batch, cnt);

    int nsb = (n + SCAN_EPB - 1) / SCAN_EPB;
    scan1<<<nsb, TPB, 0, stream>>>(deg, n, offs, bsums);
    scan2<<<1, 64, 0, stream>>>(bsums, nsb);
    scan3<<<(n + TPB - 1) / TPB, TPB, 0, stream>>>(offs, n, bsums);
    build_csr<<<(E + TPB - 1) / TPB, TPB, 0, stream>>>(ei, E, offs, cursor, adj);

    gemm1<<<(n + BM - 1) / BM, 256, 0, stream>>>(x, W1, dinv, hs1, n);
    gather1<<<(n + 3) / 4, 256, 0, stream>>>(hs1, adj, offs, deg, dinv, b1, gs1, n);
    gather2_pool<<<(n + 3) / 4, 256, 0, stream>>>(gs1, adj, offs, deg, dinv, batch, poolsum, n);
    head<<<G, 256, 0, stream>>>(poolsum, cnt, W2, b2, Wg, bg, out, G);
}

// Round 4
// 622.367 us; speedup vs baseline: 1.1599x; 1.1599x over previous
//
#include <hip/hip_runtime.h>

// ---------------------------------------------------------------------------
// ContrastiveGNN: 2-layer GCN + global mean pool + linear head.  All f32.
//
//   hs1[v]   = (x[v] @ W1) * dinv[v]            (GEMM1, fused scale)
//   g1[v]    = relu(dinv[v]*(hs1[v] + sum_{u->v} hs1[u]) + b1)
//   gs1[v]   = g1[v] * dinv[v]                  (gather1)
//   a2[v]    = dinv[v]*(gs1[v] + sum_{u->v} gs1[u])
//   pool[g]  = mean_{v in g} a2[v]              (gather2, fused atomic pool)
//   emb      = pool @ W2 + b2 ; logits = emb @ Wg + bg   (tiny head)
//
// Gather structure = round-1 verified mapping (1 wave/node, 64 lanes x
// float2 = full 512B row), with the neighbor loop unrolled x4: 4
// wave-uniform s_load'ed indices -> 4 independent row loads in flight
// into 4 accumulators. NOTE: half-wave + __shfl restructure (rounds 2/3)
// produced identical wrong results in f16 AND f32 -- do not reintroduce.
// ---------------------------------------------------------------------------

#define TPB 256

__global__ void count_deg(const int* __restrict__ ei, int E, int* __restrict__ deg) {
    int e = blockIdx.x * blockDim.x + threadIdx.x;
    if (e < E) atomicAdd(&deg[ei[E + e]], 1);  // dst = edge_index[1][e]
}

__global__ void dinv_cnt(const int* __restrict__ deg, float* __restrict__ dinv, int n,
                         const int* __restrict__ batch, int* __restrict__ cnt) {
    int v = blockIdx.x * blockDim.x + threadIdx.x;
    if (v < n) {
        dinv[v] = rsqrtf((float)(deg[v] + 1));   // +1 = self loop
        atomicAdd(&cnt[batch[v]], 1);
    }
}

// ---- exclusive scan of deg -> offs ----
#define SCAN_EPT 8
#define SCAN_EPB (TPB * SCAN_EPT)   // 2048

__global__ void scan1(const int* __restrict__ deg, int n,
                      int* __restrict__ offs, int* __restrict__ bsums) {
    __shared__ int s[TPB];
    int t = threadIdx.x;
    int base = blockIdx.x * SCAN_EPB + t * SCAN_EPT;
    int vals[SCAN_EPT];
    int tot = 0;
#pragma unroll
    for (int i = 0; i < SCAN_EPT; ++i) {
        int idx = base + i;
        int v = (idx < n) ? deg[idx] : 0;
        vals[i] = tot;
        tot += v;
    }
    s[t] = tot;
    __syncthreads();
    for (int off = 1; off < TPB; off <<= 1) {
        int v = (t >= off) ? s[t - off] : 0;
        __syncthreads();
        s[t] += v;
        __syncthreads();
    }
    int excl = s[t] - tot;
#pragma unroll
    for (int i = 0; i < SCAN_EPT; ++i) {
        int idx = base + i;
        if (idx < n) offs[idx] = excl + vals[i];
    }
    if (t == TPB - 1) bsums[blockIdx.x] = s[t];
}

__global__ void scan2(int* __restrict__ bsums, int nb) {
    if (threadIdx.x == 0 && blockIdx.x == 0) {
        int run = 0;
        for (int i = 0; i < nb; ++i) { int v = bsums[i]; bsums[i] = run; run += v; }
    }
}

__global__ void scan3(int* __restrict__ offs, int n, const int* __restrict__ bsums) {
    int i = blockIdx.x * blockDim.x + threadIdx.x;
    if (i < n) offs[i] += bsums[i / SCAN_EPB];
}

__global__ void build_csr(const int* __restrict__ ei, int E, const int* __restrict__ offs,
                          int* __restrict__ cursor, int* __restrict__ adj) {
    int e = blockIdx.x * blockDim.x + threadIdx.x;
    if (e < E) {
        int s = ei[e], d = ei[E + e];
        int pos = offs[d] + atomicAdd(&cursor[d], 1);
        adj[pos] = s;
    }
}

// ---- GEMM1: hs1 = (x @ W1) * dinv[row].  M=n, N=128, K=128, f32 ----
#define BM 64
#define BN 128
#define BK 32
#define TM 4
#define TN 8

__global__ __launch_bounds__(256) void gemm1(const float* __restrict__ X,
                                             const float* __restrict__ W,
                                             const float* __restrict__ dinv,
                                             float* __restrict__ out, int n) {
    __shared__ float As[BK][BM + 1];
    __shared__ float Bs[BK][BN];
    int t = threadIdx.x;
    int tx = t % 16, ty = t / 16;
    int rowBase = blockIdx.x * BM;
    float acc[TM][TN] = {};
    for (int k0 = 0; k0 < 128; k0 += BK) {
#pragma unroll
        for (int i = 0; i < (BM * BK) / 256; ++i) {
            int e = i * 256 + t;
            int r = e / BK, kk = e % BK;
            int gr = rowBase + r;
            As[kk][r] = (gr < n) ? X[(size_t)gr * 128 + k0 + kk] : 0.f;
        }
#pragma unroll
        for (int i = 0; i < (BK * BN) / 256; ++i) {
            int e = i * 256 + t;
            int kk = e / BN, c = e % BN;
            Bs[kk][c] = W[(size_t)(k0 + kk) * 128 + c];
        }
        __syncthreads();
#pragma unroll
        for (int kk = 0; kk < BK; ++kk) {
            float a[TM], b[TN];
#pragma unroll
            for (int m = 0; m < TM; ++m) a[m] = As[kk][ty * TM + m];
#pragma unroll
            for (int j = 0; j < TN; ++j) b[j] = Bs[kk][tx * TN + j];
#pragma unroll
            for (int m = 0; m < TM; ++m)
#pragma unroll
                for (int j = 0; j < TN; ++j)
                    acc[m][j] += a[m] * b[j];
        }
        __syncthreads();
    }
#pragma unroll
    for (int m = 0; m < TM; ++m) {
        int gr = rowBase + ty * TM + m;
        if (gr < n) {
            float s = dinv[gr];
#pragma unroll
            for (int j = 0; j < TN; ++j)
                out[(size_t)gr * 128 + tx * TN + j] = acc[m][j] * s;
        }
    }
}

// ---- gather1: g1 = relu(dinv*(self+neighbors)+b1); store gs1 = g1*dinv ----
__global__ void gather1(const float* __restrict__ hs, const int* __restrict__ adj,
                        const int* __restrict__ offs, const int* __restrict__ deg,
                        const float* __restrict__ dinv, const float* __restrict__ b1,
                        float* __restrict__ gs, int n) {
    int wave = threadIdx.x >> 6;
    int lane = threadIdx.x & 63;
    int v = blockIdx.x * 4 + wave;
    if (v >= n) return;
    const float2* self = (const float2*)(hs + (size_t)v * 128);
    float2 a0 = self[lane];                          // self loop in acc0
    float2 a1 = make_float2(0.f, 0.f);
    float2 a2 = make_float2(0.f, 0.f);
    float2 a3 = make_float2(0.f, 0.f);
    int start = offs[v], d = deg[v];
    int i = 0;
    for (; i + 3 < d; i += 4) {                      // 4 rows in flight
        int u0 = adj[start + i];
        int u1 = adj[start + i + 1];
        int u2 = adj[start + i + 2];
        int u3 = adj[start + i + 3];
        float2 r0 = ((const float2*)(hs + (size_t)u0 * 128))[lane];
        float2 r1 = ((const float2*)(hs + (size_t)u1 * 128))[lane];
        float2 r2 = ((const float2*)(hs + (size_t)u2 * 128))[lane];
        float2 r3 = ((const float2*)(hs + (size_t)u3 * 128))[lane];
        a0.x += r0.x; a0.y += r0.y;
        a1.x += r1.x; a1.y += r1.y;
        a2.x += r2.x; a2.y += r2.y;
        a3.x += r3.x; a3.y += r3.y;
    }
    for (; i < d; ++i) {
        int u = adj[start + i];
        float2 r = ((const float2*)(hs + (size_t)u * 128))[lane];
        a0.x += r.x; a0.y += r.y;
    }
    float accx = (a0.x + a1.x) + (a2.x + a3.x);
    float accy = (a0.y + a1.y) + (a2.y + a3.y);
    float dv = dinv[v];
    float2 bb = ((const float2*)b1)[lane];
    float g0 = fmaxf(accx * dv + bb.x, 0.f);
    float g1 = fmaxf(accy * dv + bb.y, 0.f);
    float2* o = (float2*)(gs + (size_t)v * 128);
    o[lane] = make_float2(g0 * dv, g1 * dv);
}

// ---- gather2 + fused atomic mean-pool accumulate ----
__global__ void gather2_pool(const float* __restrict__ gs, const int* __restrict__ adj,
                             const int* __restrict__ offs, const int* __restrict__ deg,
                             const float* __restrict__ dinv, const int* __restrict__ batch,
                             float* __restrict__ poolsum, int n) {
    int wave = threadIdx.x >> 6;
    int lane = threadIdx.x & 63;
    int v = blockIdx.x * 4 + wave;
    if (v >= n) return;
    const float2* self = (const float2*)(gs + (size_t)v * 128);
    float2 a0 = self[lane];
    float2 a1 = make_float2(0.f, 0.f);
    float2 a2 = make_float2(0.f, 0.f);
    float2 a3 = make_float2(0.f, 0.f);
    int start = offs[v], d = deg[v];
    int i = 0;
    for (; i + 3 < d; i += 4) {
        int u0 = adj[start + i];
        int u1 = adj[start + i + 1];
        int u2 = adj[start + i + 2];
        int u3 = adj[start + i + 3];
        float2 r0 = ((const float2*)(gs + (size_t)u0 * 128))[lane];
        float2 r1 = ((const float2*)(gs + (size_t)u1 * 128))[lane];
        float2 r2 = ((const float2*)(gs + (size_t)u2 * 128))[lane];
        float2 r3 = ((const float2*)(gs + (size_t)u3 * 128))[lane];
        a0.x += r0.x; a0.y += r0.y;
        a1.x += r1.x; a1.y += r1.y;
        a2.x += r2.x; a2.y += r2.y;
        a3.x += r3.x; a3.y += r3.y;
    }
    for (; i < d; ++i) {
        int u = adj[start + i];
        float2 r = ((const float2*)(gs + (size_t)u * 128))[lane];
        a0.x += r.x; a0.y += r.y;
    }
    float accx = (a0.x + a1.x) + (a2.x + a3.x);
    float accy = (a0.y + a1.y) + (a2.y + a3.y);
    float dv = dinv[v];
    float* p = poolsum + (size_t)batch[v] * 128;
    atomicAdd(&p[lane * 2 + 0], accx * dv);
    atomicAdd(&p[lane * 2 + 1], accy * dv);
}

// ---- head: emb = (pool/cnt) @ W2 + b2 ; logits = emb @ Wg + bg ----
__global__ void head(const float* __restrict__ poolsum, const int* __restrict__ cnt,
                     const float* __restrict__ W2, const float* __restrict__ b2,
                     const float* __restrict__ Wg, const float* __restrict__ bg,
                     float* __restrict__ out, int G) {
    __shared__ float pm[128];
    __shared__ float emb[256];
    int g = blockIdx.x, t = threadIdx.x;
    float inv = 1.f / fmaxf((float)cnt[g], 1.f);
    if (t < 128) pm[t] = poolsum[(size_t)g * 128 + t] * inv;
    __syncthreads();
    float acc = b2[t];
    for (int k = 0; k < 128; ++k) acc += pm[k] * W2[k * 256 + t];
    out[(size_t)g * 256 + t] = acc;
    emb[t] = acc;
    __syncthreads();
    if (t < 16) {
        float a = bg[t];
        for (int j = 0; j < 256; ++j) a += emb[j] * Wg[j * 16 + t];
        out[(size_t)G * 256 + g * 16 + t] = a;
    }
}

extern "C" void kernel_launch(void* const* d_in, const int* in_sizes, int n_in,
                              void* d_out, int out_size, void* d_ws, size_t ws_size,
                              hipStream_t stream) {
    const float* x     = (const float*)d_in[0];
    const int*   ei    = (const int*)d_in[1];
    const int*   batch = (const int*)d_in[2];
    const float* W1    = (const float*)d_in[4];
    const float* b1    = (const float*)d_in[5];
    const float* W2    = (const float*)d_in[6];
    const float* b2    = (const float*)d_in[7];
    const float* Wg    = (const float*)d_in[8];
    const float* bg    = (const float*)d_in[9];
    float* out = (float*)d_out;

    int n = in_sizes[0] / 128;
    int E = in_sizes[1] / 2;
    int G = out_size / (256 + 16);

    char* ws = (char*)d_ws;
    auto alloc = [&](size_t bytes) {
        char* p = ws;
        ws += (bytes + 255) & ~(size_t)255;
        return p;
    };
    int*   deg     = (int*)alloc((size_t)n * 4);
    float* dinv    = (float*)alloc((size_t)n * 4);
    int*   offs    = (int*)alloc((size_t)n * 4);
    int*   cursor  = (int*)alloc((size_t)n * 4);
    int*   adj     = (int*)alloc((size_t)E * 4);
    int*   bsums   = (int*)alloc(256 * 4);
    int*   cnt     = (int*)alloc((size_t)G * 4);
    float* poolsum = (float*)alloc((size_t)G * 128 * 4);
    float* hs1     = (float*)alloc((size_t)n * 128 * 4);
    float* gs1     = (float*)alloc((size_t)n * 128 * 4);

    hipMemsetAsync(deg, 0, (size_t)n * 4, stream);
    hipMemsetAsync(cursor, 0, (size_t)n * 4, stream);
    hipMemsetAsync(cnt, 0, (size_t)G * 4, stream);
    hipMemsetAsync(poolsum, 0, (size_t)G * 128 * 4, stream);

    count_deg<<<(E + TPB - 1) / TPB, TPB, 0, stream>>>(ei, E, deg);
    dinv_cnt<<<(n + TPB - 1) / TPB, TPB, 0, stream>>>(deg, dinv, n, batch, cnt);

    int nsb = (n + SCAN_EPB - 1) / SCAN_EPB;
    scan1<<<nsb, TPB, 0, stream>>>(deg, n, offs, bsums);
    scan2<<<1, 64, 0, stream>>>(bsums, nsb);
    scan3<<<(n + TPB - 1) / TPB, TPB, 0, stream>>>(offs, n, bsums);
    build_csr<<<(E + TPB - 1) / TPB, TPB, 0, stream>>>(ei, E, offs, cursor, adj);

    gemm1<<<(n + BM - 1) / BM, 256, 0, stream>>>(x, W1, dinv, hs1, n);
    gather1<<<(n + 3) / 4, 256, 0, stream>>>(hs1, adj, offs, deg, dinv, b1, gs1, n);
    gather2_pool<<<(n + 3) / 4, 256, 0, stream>>>(gs1, adj, offs, deg, dinv, batch, poolsum, n);
    head<<<G, 256, 0, stream>>>(poolsum, cnt, W2, b2, Wg, bg, out, G);
}

// Round 5
// 532.506 us; speedup vs baseline: 1.3556x; 1.1688x over previous
//
#include <hip/hip_runtime.h>
#include <hip/hip_fp16.h>

// ---------------------------------------------------------------------------
// ContrastiveGNN: 2-layer GCN + global mean pool + linear head.
//
//   hs1[v]   = (x[v] @ W1) * dinv[v]            (GEMM1 f32 math, f16 store)
//   g1[v]    = relu(dinv[v]*(hs1[v] + sum_{u->v} hs1[u]) + b1)
//   gs1[v]   = g1[v] * dinv[v]                  (gather1, f32 math, f16 store)
//   a2[v]    = dinv[v]*(gs1[v] + sum_{u->v} gs1[u])
//   pool[g]  = mean_{v in g} a2[v]              (gather2, fused atomic pool, f32)
//   emb      = pool @ W2 + b2 ; logits = emb @ Wg + bg   (tiny head, f32)
//
// Gather structure = round-4 VERIFIED mapping: 1 wave/node, 64 lanes, lane
// holds features [2*lane, 2*lane+1] (half2), neighbor loop unrolled 8/4/1
// with wave-uniform scalar index loads -> up to 8 rows in flight.
// DO NOT reintroduce the half-wave + __shfl restructure (rounds 2/3: wrong
// results independent of dtype).  Intermediates f16: round-3 A/B proved the
// round-2 failure was the structure, not the dtype.
// ---------------------------------------------------------------------------

#define TPB 256

__global__ void count_deg(const int* __restrict__ ei, int E, int* __restrict__ deg) {
    int e = blockIdx.x * blockDim.x + threadIdx.x;
    if (e < E) atomicAdd(&deg[ei[E + e]], 1);  // dst = edge_index[1][e]
}

__global__ void dinv_cnt(const int* __restrict__ deg, float* __restrict__ dinv, int n,
                         const int* __restrict__ batch, int* __restrict__ cnt) {
    int v = blockIdx.x * blockDim.x + threadIdx.x;
    if (v < n) {
        dinv[v] = rsqrtf((float)(deg[v] + 1));   // +1 = self loop
        atomicAdd(&cnt[batch[v]], 1);
    }
}

// ---- exclusive scan of deg -> offs ----
#define SCAN_EPT 8
#define SCAN_EPB (TPB * SCAN_EPT)   // 2048

__global__ void scan1(const int* __restrict__ deg, int n,
                      int* __restrict__ offs, int* __restrict__ bsums) {
    __shared__ int s[TPB];
    int t = threadIdx.x;
    int base = blockIdx.x * SCAN_EPB + t * SCAN_EPT;
    int vals[SCAN_EPT];
    int tot = 0;
#pragma unroll
    for (int i = 0; i < SCAN_EPT; ++i) {
        int idx = base + i;
        int v = (idx < n) ? deg[idx] : 0;
        vals[i] = tot;
        tot += v;
    }
    s[t] = tot;
    __syncthreads();
    for (int off = 1; off < TPB; off <<= 1) {
        int v = (t >= off) ? s[t - off] : 0;
        __syncthreads();
        s[t] += v;
        __syncthreads();
    }
    int excl = s[t] - tot;
#pragma unroll
    for (int i = 0; i < SCAN_EPT; ++i) {
        int idx = base + i;
        if (idx < n) offs[idx] = excl + vals[i];
    }
    if (t == TPB - 1) bsums[blockIdx.x] = s[t];
}

__global__ void scan2(int* __restrict__ bsums, int nb) {
    if (threadIdx.x == 0 && blockIdx.x == 0) {
        int run = 0;
        for (int i = 0; i < nb; ++i) { int v = bsums[i]; bsums[i] = run; run += v; }
    }
}

__global__ void scan3(int* __restrict__ offs, int n, const int* __restrict__ bsums) {
    int i = blockIdx.x * blockDim.x + threadIdx.x;
    if (i < n) offs[i] += bsums[i / SCAN_EPB];
}

__global__ void build_csr(const int* __restrict__ ei, int E, const int* __restrict__ offs,
                          int* __restrict__ cursor, int* __restrict__ adj) {
    int e = blockIdx.x * blockDim.x + threadIdx.x;
    if (e < E) {
        int s = ei[e], d = ei[E + e];
        int pos = offs[d] + atomicAdd(&cursor[d], 1);
        adj[pos] = s;
    }
}

// ---- GEMM1: hs1 = (x @ W1) * dinv[row], f32 math, f16 store ----
#define BM 64
#define BN 128
#define BK 32
#define TM 4
#define TN 8

__global__ __launch_bounds__(256) void gemm1(const float* __restrict__ X,
                                             const float* __restrict__ W,
                                             const float* __restrict__ dinv,
                                             __half* __restrict__ out, int n) {
    __shared__ float As[BK][BM + 1];
    __shared__ float Bs[BK][BN];
    int t = threadIdx.x;
    int tx = t % 16, ty = t / 16;
    int rowBase = blockIdx.x * BM;
    float acc[TM][TN] = {};
    for (int k0 = 0; k0 < 128; k0 += BK) {
#pragma unroll
        for (int i = 0; i < (BM * BK) / 256; ++i) {
            int e = i * 256 + t;
            int r = e / BK, kk = e % BK;
            int gr = rowBase + r;
            As[kk][r] = (gr < n) ? X[(size_t)gr * 128 + k0 + kk] : 0.f;
        }
#pragma unroll
        for (int i = 0; i < (BK * BN) / 256; ++i) {
            int e = i * 256 + t;
            int kk = e / BN, c = e % BN;
            Bs[kk][c] = W[(size_t)(k0 + kk) * 128 + c];
        }
        __syncthreads();
#pragma unroll
        for (int kk = 0; kk < BK; ++kk) {
            float a[TM], b[TN];
#pragma unroll
            for (int m = 0; m < TM; ++m) a[m] = As[kk][ty * TM + m];
#pragma unroll
            for (int j = 0; j < TN; ++j) b[j] = Bs[kk][tx * TN + j];
#pragma unroll
            for (int m = 0; m < TM; ++m)
#pragma unroll
                for (int j = 0; j < TN; ++j)
                    acc[m][j] += a[m] * b[j];
        }
        __syncthreads();
    }
#pragma unroll
    for (int m = 0; m < TM; ++m) {
        int gr = rowBase + ty * TM + m;
        if (gr < n) {
            float s = dinv[gr];
            __half2 q0 = __floats2half2_rn(acc[m][0] * s, acc[m][1] * s);
            __half2 q1 = __floats2half2_rn(acc[m][2] * s, acc[m][3] * s);
            __half2 q2 = __floats2half2_rn(acc[m][4] * s, acc[m][5] * s);
            __half2 q3 = __floats2half2_rn(acc[m][6] * s, acc[m][7] * s);
            uint4 w;
            w.x = *(unsigned int*)&q0;
            w.y = *(unsigned int*)&q1;
            w.z = *(unsigned int*)&q2;
            w.w = *(unsigned int*)&q3;
            ((uint4*)(out + (size_t)gr * 128))[tx] = w;   // 16B/thread, 256B row
        }
    }
}

// lane holds features [2*lane, 2*lane+1]: one half2 (4B) per lane, 256B row.
__device__ __forceinline__ void acc_h2(unsigned int rv, float2& a) {
    float2 f = __half22float2(*(__half2*)&rv);
    a.x += f.x; a.y += f.y;
}
#define ROWP(buf, u) ((const unsigned int*)((buf) + (size_t)(u) * 128))

// ---- gather1: g1 = relu(dinv*(self+neighbors)+b1); store gs1 = g1*dinv ----
__global__ void gather1(const __half* __restrict__ hs, const int* __restrict__ adj,
                        const int* __restrict__ offs, const int* __restrict__ deg,
                        const float* __restrict__ dinv, const float* __restrict__ b1,
                        __half* __restrict__ gs, int n) {
    int wave = threadIdx.x >> 6;
    int lane = threadIdx.x & 63;
    int v = blockIdx.x * 4 + wave;
    if (v >= n) return;
    float2 a0 = make_float2(0.f, 0.f), a1 = a0, a2 = a0, a3 = a0;
    acc_h2(ROWP(hs, v)[lane], a0);                   // self loop
    int start = offs[v], d = deg[v];
    int i = 0;
    for (; i + 7 < d; i += 8) {                      // 8 rows in flight
        int u0 = adj[start + i + 0], u1 = adj[start + i + 1];
        int u2 = adj[start + i + 2], u3 = adj[start + i + 3];
        int u4 = adj[start + i + 4], u5 = adj[start + i + 5];
        int u6 = adj[start + i + 6], u7 = adj[start + i + 7];
        unsigned int r0 = ROWP(hs, u0)[lane], r1 = ROWP(hs, u1)[lane];
        unsigned int r2 = ROWP(hs, u2)[lane], r3 = ROWP(hs, u3)[lane];
        unsigned int r4 = ROWP(hs, u4)[lane], r5 = ROWP(hs, u5)[lane];
        unsigned int r6 = ROWP(hs, u6)[lane], r7 = ROWP(hs, u7)[lane];
        acc_h2(r0, a0); acc_h2(r1, a1); acc_h2(r2, a2); acc_h2(r3, a3);
        acc_h2(r4, a0); acc_h2(r5, a1); acc_h2(r6, a2); acc_h2(r7, a3);
    }
    for (; i + 3 < d; i += 4) {
        int u0 = adj[start + i + 0], u1 = adj[start + i + 1];
        int u2 = adj[start + i + 2], u3 = adj[start + i + 3];
        unsigned int r0 = ROWP(hs, u0)[lane], r1 = ROWP(hs, u1)[lane];
        unsigned int r2 = ROWP(hs, u2)[lane], r3 = ROWP(hs, u3)[lane];
        acc_h2(r0, a0); acc_h2(r1, a1); acc_h2(r2, a2); acc_h2(r3, a3);
    }
    for (; i < d; ++i) acc_h2(ROWP(hs, adj[start + i])[lane], a0);
    float accx = (a0.x + a1.x) + (a2.x + a3.x);
    float accy = (a0.y + a1.y) + (a2.y + a3.y);
    float dv = dinv[v];
    float2 bb = ((const float2*)b1)[lane];
    float g0 = fmaxf(accx * dv + bb.x, 0.f) * dv;
    float g1 = fmaxf(accy * dv + bb.y, 0.f) * dv;
    __half2 h = __floats2half2_rn(g0, g1);
    ((unsigned int*)(gs + (size_t)v * 128))[lane] = *(unsigned int*)&h;
}

// ---- gather2 + fused atomic mean-pool accumulate ----
__global__ void gather2_pool(const __half* __restrict__ gs, const int* __restrict__ adj,
                             const int* __restrict__ offs, const int* __restrict__ deg,
                             const float* __restrict__ dinv, const int* __restrict__ batch,
                             float* __restrict__ poolsum, int n) {
    int wave = threadIdx.x >> 6;
    int lane = threadIdx.x & 63;
    int v = blockIdx.x * 4 + wave;
    if (v >= n) return;
    float2 a0 = make_float2(0.f, 0.f), a1 = a0, a2 = a0, a3 = a0;
    acc_h2(ROWP(gs, v)[lane], a0);
    int start = offs[v], d = deg[v];
    int i = 0;
    for (; i + 7 < d; i += 8) {
        int u0 = adj[start + i + 0], u1 = adj[start + i + 1];
        int u2 = adj[start + i + 2], u3 = adj[start + i + 3];
        int u4 = adj[start + i + 4], u5 = adj[start + i + 5];
        int u6 = adj[start + i + 6], u7 = adj[start + i + 7];
        unsigned int r0 = ROWP(gs, u0)[lane], r1 = ROWP(gs, u1)[lane];
        unsigned int r2 = ROWP(gs, u2)[lane], r3 = ROWP(gs, u3)[lane];
        unsigned int r4 = ROWP(gs, u4)[lane], r5 = ROWP(gs, u5)[lane];
        unsigned int r6 = ROWP(gs, u6)[lane], r7 = ROWP(gs, u7)[lane];
        acc_h2(r0, a0); acc_h2(r1, a1); acc_h2(r2, a2); acc_h2(r3, a3);
        acc_h2(r4, a0); acc_h2(r5, a1); acc_h2(r6, a2); acc_h2(r7, a3);
    }
    for (; i + 3 < d; i += 4) {
        int u0 = adj[start + i + 0], u1 = adj[start + i + 1];
        int u2 = adj[start + i + 2], u3 = adj[start + i + 3];
        unsigned int r0 = ROWP(gs, u0)[lane], r1 = ROWP(gs, u1)[lane];
        unsigned int r2 = ROWP(gs, u2)[lane], r3 = ROWP(gs, u3)[lane];
        acc_h2(r0, a0); acc_h2(r1, a1); acc_h2(r2, a2); acc_h2(r3, a3);
    }
    for (; i < d; ++i) acc_h2(ROWP(gs, adj[start + i])[lane], a0);
    float accx = (a0.x + a1.x) + (a2.x + a3.x);
    float accy = (a0.y + a1.y) + (a2.y + a3.y);
    float dv = dinv[v];
    float* p = poolsum + (size_t)batch[v] * 128;
    atomicAdd(&p[lane * 2 + 0], accx * dv);
    atomicAdd(&p[lane * 2 + 1], accy * dv);
}

// ---- head: emb = (pool/cnt) @ W2 + b2 ; logits = emb @ Wg + bg ----
__global__ void head(const float* __restrict__ poolsum, const int* __restrict__ cnt,
                     const float* __restrict__ W2, const float* __restrict__ b2,
                     const float* __restrict__ Wg, const float* __restrict__ bg,
                     float* __restrict__ out, int G) {
    __shared__ float pm[128];
    __shared__ float emb[256];
    int g = blockIdx.x, t = threadIdx.x;
    float inv = 1.f / fmaxf((float)cnt[g], 1.f);
    if (t < 128) pm[t] = poolsum[(size_t)g * 128 + t] * inv;
    __syncthreads();
    float acc = b2[t];
    for (int k = 0; k < 128; ++k) acc += pm[k] * W2[k * 256 + t];
    out[(size_t)g * 256 + t] = acc;
    emb[t] = acc;
    __syncthreads();
    if (t < 16) {
        float a = bg[t];
        for (int j = 0; j < 256; ++j) a += emb[j] * Wg[j * 16 + t];
        out[(size_t)G * 256 + g * 16 + t] = a;
    }
}

extern "C" void kernel_launch(void* const* d_in, const int* in_sizes, int n_in,
                              void* d_out, int out_size, void* d_ws, size_t ws_size,
                              hipStream_t stream) {
    const float* x     = (const float*)d_in[0];
    const int*   ei    = (const int*)d_in[1];
    const int*   batch = (const int*)d_in[2];
    const float* W1    = (const float*)d_in[4];
    const float* b1    = (const float*)d_in[5];
    const float* W2    = (const float*)d_in[6];
    const float* b2    = (const float*)d_in[7];
    const float* Wg    = (const float*)d_in[8];
    const float* bg    = (const float*)d_in[9];
    float* out = (float*)d_out;

    int n = in_sizes[0] / 128;
    int E = in_sizes[1] / 2;
    int G = out_size / (256 + 16);

    char* ws = (char*)d_ws;
    auto alloc = [&](size_t bytes) {
        char* p = ws;
        ws += (bytes + 255) & ~(size_t)255;
        return p;
    };
    int*    deg     = (int*)alloc((size_t)n * 4);
    float*  dinv    = (float*)alloc((size_t)n * 4);
    int*    offs    = (int*)alloc((size_t)n * 4);
    int*    cursor  = (int*)alloc((size_t)n * 4);
    int*    adj     = (int*)alloc((size_t)E * 4);
    int*    bsums   = (int*)alloc(256 * 4);
    int*    cnt     = (int*)alloc((size_t)G * 4);
    float*  poolsum = (float*)alloc((size_t)G * 128 * 4);
    __half* hs1     = (__half*)alloc((size_t)n * 128 * 2);
    __half* gs1     = (__half*)alloc((size_t)n * 128 * 2);

    hipMemsetAsync(deg, 0, (size_t)n * 4, stream);
    hipMemsetAsync(cursor, 0, (size_t)n * 4, stream);
    hipMemsetAsync(cnt, 0, (size_t)G * 4, stream);
    hipMemsetAsync(poolsum, 0, (size_t)G * 128 * 4, stream);

    count_deg<<<(E + TPB - 1) / TPB, TPB, 0, stream>>>(ei, E, deg);
    dinv_cnt<<<(n + TPB - 1) / TPB, TPB, 0, stream>>>(deg, dinv, n, batch, cnt);

    int nsb = (n + SCAN_EPB - 1) / SCAN_EPB;
    scan1<<<nsb, TPB, 0, stream>>>(deg, n, offs, bsums);
    scan2<<<1, 64, 0, stream>>>(bsums, nsb);
    scan3<<<(n + TPB - 1) / TPB, TPB, 0, stream>>>(offs, n, bsums);
    build_csr<<<(E + TPB - 1) / TPB, TPB, 0, stream>>>(ei, E, offs, cursor, adj);

    gemm1<<<(n + BM - 1) / BM, 256, 0, stream>>>(x, W1, dinv, hs1, n);
    gather1<<<(n + 3) / 4, 256, 0, stream>>>(hs1, adj, offs, deg, dinv, b1, gs1, n);
    gather2_pool<<<(n + 3) / 4, 256, 0, stream>>>(gs1, adj, offs, deg, dinv, batch, poolsum, n);
    head<<<G, 256, 0, stream>>>(poolsum, cnt, W2, b2, Wg, bg, out, G);
}

// Round 6
// 525.899 us; speedup vs baseline: 1.3727x; 1.0126x over previous
//
#include <hip/hip_runtime.h>
#include <hip/hip_fp16.h>

// ---------------------------------------------------------------------------
// ContrastiveGNN: 2-layer GCN + global mean pool + linear head.
//
//   hs1[v]   = (x[v] @ W1) * dinv[v]            (GEMM1 f32 math, f16 store)
//   g1[v]    = relu(dinv[v]*(hs1[v] + sum_{u->v} hs1[u]) + b1)
//   gs1[v]   = g1[v] * dinv[v]                  (gather1, f32 math, f16 store)
//   a2[v]    = dinv[v]*(gs1[v] + sum_{u->v} gs1[u])
//   pool[g]  = mean_{v in g} a2[v]              (gather2, fused atomic pool)
//   emb      = pool @ W2 + b2 ; logits = emb @ Wg + bg   (tiny head)
//
// Gathers: 2 adjacent nodes per wave, 8 rows in flight per node = 16
// outstanding 256B row loads/wave (r5 had 8; r5 profile showed latency-
// bound: halving bytes only cut time 24%).  Lane mapping unchanged from
// verified r4/r5: lane holds features [2*lane, 2*lane+1] (half2).
// DO NOT reintroduce the half-wave + __shfl restructure (rounds 2/3).
// ---------------------------------------------------------------------------

#define TPB 256

__global__ void count_deg(const int* __restrict__ ei, int E, int* __restrict__ deg) {
    int e = blockIdx.x * blockDim.x + threadIdx.x;
    if (e < E) atomicAdd(&deg[ei[E + e]], 1);  // dst = edge_index[1][e]
}

__global__ void dinv_cnt(const int* __restrict__ deg, float* __restrict__ dinv, int n,
                         const int* __restrict__ batch, int* __restrict__ cnt) {
    int v = blockIdx.x * blockDim.x + threadIdx.x;
    if (v < n) {
        dinv[v] = rsqrtf((float)(deg[v] + 1));   // +1 = self loop
        atomicAdd(&cnt[batch[v]], 1);
    }
}

// ---- exclusive scan of deg -> offs ----
#define SCAN_EPT 8
#define SCAN_EPB (TPB * SCAN_EPT)   // 2048

__global__ void scan1(const int* __restrict__ deg, int n,
                      int* __restrict__ offs, int* __restrict__ bsums) {
    __shared__ int s[TPB];
    int t = threadIdx.x;
    int base = blockIdx.x * SCAN_EPB + t * SCAN_EPT;
    int vals[SCAN_EPT];
    int tot = 0;
#pragma unroll
    for (int i = 0; i < SCAN_EPT; ++i) {
        int idx = base + i;
        int v = (idx < n) ? deg[idx] : 0;
        vals[i] = tot;
        tot += v;
    }
    s[t] = tot;
    __syncthreads();
    for (int off = 1; off < TPB; off <<= 1) {
        int v = (t >= off) ? s[t - off] : 0;
        __syncthreads();
        s[t] += v;
        __syncthreads();
    }
    int excl = s[t] - tot;
#pragma unroll
    for (int i = 0; i < SCAN_EPT; ++i) {
        int idx = base + i;
        if (idx < n) offs[idx] = excl + vals[i];
    }
    if (t == TPB - 1) bsums[blockIdx.x] = s[t];
}

__global__ void scan2(int* __restrict__ bsums, int nb) {
    if (threadIdx.x == 0 && blockIdx.x == 0) {
        int run = 0;
        for (int i = 0; i < nb; ++i) { int v = bsums[i]; bsums[i] = run; run += v; }
    }
}

__global__ void scan3(int* __restrict__ offs, int n, const int* __restrict__ bsums) {
    int i = blockIdx.x * blockDim.x + threadIdx.x;
    if (i < n) offs[i] += bsums[i / SCAN_EPB];
}

__global__ void build_csr(const int* __restrict__ ei, int E, const int* __restrict__ offs,
                          int* __restrict__ cursor, int* __restrict__ adj) {
    int e = blockIdx.x * blockDim.x + threadIdx.x;
    if (e < E) {
        int s = ei[e], d = ei[E + e];
        int pos = offs[d] + atomicAdd(&cursor[d], 1);
        adj[pos] = s;
    }
}

// ---- GEMM1: hs1 = (x @ W1) * dinv[row], f32 math, f16 store ----
#define BM 64
#define BN 128
#define BK 32
#define TM 4
#define TN 8

__global__ __launch_bounds__(256) void gemm1(const float* __restrict__ X,
                                             const float* __restrict__ W,
                                             const float* __restrict__ dinv,
                                             __half* __restrict__ out, int n) {
    __shared__ float As[BK][BM + 1];
    __shared__ float Bs[BK][BN];
    int t = threadIdx.x;
    int tx = t % 16, ty = t / 16;
    int rowBase = blockIdx.x * BM;
    float acc[TM][TN] = {};
    for (int k0 = 0; k0 < 128; k0 += BK) {
#pragma unroll
        for (int i = 0; i < (BM * BK) / 256; ++i) {
            int e = i * 256 + t;
            int r = e / BK, kk = e % BK;
            int gr = rowBase + r;
            As[kk][r] = (gr < n) ? X[(size_t)gr * 128 + k0 + kk] : 0.f;
        }
#pragma unroll
        for (int i = 0; i < (BK * BN) / 256; ++i) {
            int e = i * 256 + t;
            int kk = e / BN, c = e % BN;
            Bs[kk][c] = W[(size_t)(k0 + kk) * 128 + c];
        }
        __syncthreads();
#pragma unroll
        for (int kk = 0; kk < BK; ++kk) {
            float a[TM], b[TN];
#pragma unroll
            for (int m = 0; m < TM; ++m) a[m] = As[kk][ty * TM + m];
#pragma unroll
            for (int j = 0; j < TN; ++j) b[j] = Bs[kk][tx * TN + j];
#pragma unroll
            for (int m = 0; m < TM; ++m)
#pragma unroll
                for (int j = 0; j < TN; ++j)
                    acc[m][j] += a[m] * b[j];
        }
        __syncthreads();
    }
#pragma unroll
    for (int m = 0; m < TM; ++m) {
        int gr = rowBase + ty * TM + m;
        if (gr < n) {
            float s = dinv[gr];
            __half2 q0 = __floats2half2_rn(acc[m][0] * s, acc[m][1] * s);
            __half2 q1 = __floats2half2_rn(acc[m][2] * s, acc[m][3] * s);
            __half2 q2 = __floats2half2_rn(acc[m][4] * s, acc[m][5] * s);
            __half2 q3 = __floats2half2_rn(acc[m][6] * s, acc[m][7] * s);
            uint4 w;
            w.x = *(unsigned int*)&q0;
            w.y = *(unsigned int*)&q1;
            w.z = *(unsigned int*)&q2;
            w.w = *(unsigned int*)&q3;
            ((uint4*)(out + (size_t)gr * 128))[tx] = w;   // 16B/thread, 256B row
        }
    }
}

// lane holds features [2*lane, 2*lane+1]: one half2 (4B) per lane, 256B row.
__device__ __forceinline__ void acc_h2(unsigned int rv, float2& a) {
    float2 f = __half22float2(*(__half2*)&rv);
    a.x += f.x; a.y += f.y;
}
#define ROWP(buf, u) ((const unsigned int*)((buf) + (size_t)(u) * 128))

// per-node tail ladder (verified r5 structure): consumes [i, d) into a0..a3
#define TAIL_LADDER(buf, st, i, d, a0, a1, a2, a3)                              \
    for (; i + 7 < d; i += 8) {                                                 \
        int u0 = adj[st + i + 0], u1 = adj[st + i + 1];                         \
        int u2 = adj[st + i + 2], u3 = adj[st + i + 3];                         \
        int u4 = adj[st + i + 4], u5 = adj[st + i + 5];                         \
        int u6 = adj[st + i + 6], u7 = adj[st + i + 7];                         \
        unsigned int r0 = ROWP(buf, u0)[lane], r1 = ROWP(buf, u1)[lane];        \
        unsigned int r2 = ROWP(buf, u2)[lane], r3 = ROWP(buf, u3)[lane];        \
        unsigned int r4 = ROWP(buf, u4)[lane], r5 = ROWP(buf, u5)[lane];        \
        unsigned int r6 = ROWP(buf, u6)[lane], r7 = ROWP(buf, u7)[lane];        \
        acc_h2(r0, a0); acc_h2(r1, a1); acc_h2(r2, a2); acc_h2(r3, a3);         \
        acc_h2(r4, a0); acc_h2(r5, a1); acc_h2(r6, a2); acc_h2(r7, a3);         \
    }                                                                           \
    for (; i + 3 < d; i += 4) {                                                 \
        int u0 = adj[st + i + 0], u1 = adj[st + i + 1];                         \
        int u2 = adj[st + i + 2], u3 = adj[st + i + 3];                         \
        unsigned int r0 = ROWP(buf, u0)[lane], r1 = ROWP(buf, u1)[lane];        \
        unsigned int r2 = ROWP(buf, u2)[lane], r3 = ROWP(buf, u3)[lane];        \
        acc_h2(r0, a0); acc_h2(r1, a1); acc_h2(r2, a2); acc_h2(r3, a3);         \
    }                                                                           \
    for (; i < d; ++i) acc_h2(ROWP(buf, adj[st + i])[lane], a0);

// joint phase: 8 rows per node in flight (16 total) while both have >=8 left
#define JOINT_PHASE(buf)                                                        \
    while (i0 + 7 < d0 && i1 + 7 < d1) {                                        \
        int u0 = adj[s0 + i0 + 0], u1 = adj[s0 + i0 + 1];                       \
        int u2 = adj[s0 + i0 + 2], u3 = adj[s0 + i0 + 3];                       \
        int u4 = adj[s0 + i0 + 4], u5 = adj[s0 + i0 + 5];                       \
        int u6 = adj[s0 + i0 + 6], u7 = adj[s0 + i0 + 7];                       \
        int w0 = adj[s1 + i1 + 0], w1 = adj[s1 + i1 + 1];                       \
        int w2 = adj[s1 + i1 + 2], w3 = adj[s1 + i1 + 3];                       \
        int w4 = adj[s1 + i1 + 4], w5 = adj[s1 + i1 + 5];                       \
        int w6 = adj[s1 + i1 + 6], w7 = adj[s1 + i1 + 7];                       \
        unsigned int ra0 = ROWP(buf, u0)[lane], ra1 = ROWP(buf, u1)[lane];      \
        unsigned int ra2 = ROWP(buf, u2)[lane], ra3 = ROWP(buf, u3)[lane];      \
        unsigned int ra4 = ROWP(buf, u4)[lane], ra5 = ROWP(buf, u5)[lane];      \
        unsigned int ra6 = ROWP(buf, u6)[lane], ra7 = ROWP(buf, u7)[lane];      \
        unsigned int rb0 = ROWP(buf, w0)[lane], rb1 = ROWP(buf, w1)[lane];      \
        unsigned int rb2 = ROWP(buf, w2)[lane], rb3 = ROWP(buf, w3)[lane];      \
        unsigned int rb4 = ROWP(buf, w4)[lane], rb5 = ROWP(buf, w5)[lane];      \
        unsigned int rb6 = ROWP(buf, w6)[lane], rb7 = ROWP(buf, w7)[lane];      \
        acc_h2(ra0, A0); acc_h2(ra1, A1); acc_h2(ra2, A2); acc_h2(ra3, A3);     \
        acc_h2(ra4, A0); acc_h2(ra5, A1); acc_h2(ra6, A2); acc_h2(ra7, A3);     \
        acc_h2(rb0, B0); acc_h2(rb1, B1); acc_h2(rb2, B2); acc_h2(rb3, B3);     \
        acc_h2(rb4, B0); acc_h2(rb5, B1); acc_h2(rb6, B2); acc_h2(rb7, B3);     \
        i0 += 8; i1 += 8;                                                       \
    }

// ---- gather1: g1 = relu(dinv*(self+neighbors)+b1); store gs1 = g1*dinv ----
__global__ void gather1(const __half* __restrict__ hs, const int* __restrict__ adj,
                        const int* __restrict__ offs, const int* __restrict__ deg,
                        const float* __restrict__ dinv, const float* __restrict__ b1,
                        __half* __restrict__ gs, int n) {
    int wave = threadIdx.x >> 6;
    int lane = threadIdx.x & 63;
    int v0 = blockIdx.x * 8 + wave * 2;
    int v1 = v0 + 1;
    if (v0 >= n) return;
    bool has1 = (v1 < n);
    float2 A0 = make_float2(0.f, 0.f), A1 = A0, A2 = A0, A3 = A0;
    float2 B0 = A0, B1 = A0, B2 = A0, B3 = A0;
    acc_h2(ROWP(hs, v0)[lane], A0);                  // self loop node0
    int s0 = offs[v0], d0 = deg[v0];
    int s1 = 0, d1 = 0;
    if (has1) {
        acc_h2(ROWP(hs, v1)[lane], B0);              // self loop node1
        s1 = offs[v1]; d1 = deg[v1];
    }
    int i0 = 0, i1 = 0;
    JOINT_PHASE(hs)
    TAIL_LADDER(hs, s0, i0, d0, A0, A1, A2, A3)
    if (has1) { TAIL_LADDER(hs, s1, i1, d1, B0, B1, B2, B3) }

    float2 bb = ((const float2*)b1)[lane];
    {
        float accx = (A0.x + A1.x) + (A2.x + A3.x);
        float accy = (A0.y + A1.y) + (A2.y + A3.y);
        float dv = dinv[v0];
        float g0 = fmaxf(accx * dv + bb.x, 0.f) * dv;
        float g1 = fmaxf(accy * dv + bb.y, 0.f) * dv;
        __half2 h = __floats2half2_rn(g0, g1);
        ((unsigned int*)(gs + (size_t)v0 * 128))[lane] = *(unsigned int*)&h;
    }
    if (has1) {
        float accx = (B0.x + B1.x) + (B2.x + B3.x);
        float accy = (B0.y + B1.y) + (B2.y + B3.y);
        float dv = dinv[v1];
        float g0 = fmaxf(accx * dv + bb.x, 0.f) * dv;
        float g1 = fmaxf(accy * dv + bb.y, 0.f) * dv;
        __half2 h = __floats2half2_rn(g0, g1);
        ((unsigned int*)(gs + (size_t)v1 * 128))[lane] = *(unsigned int*)&h;
    }
}

// ---- gather2 + fused atomic mean-pool accumulate ----
__global__ void gather2_pool(const __half* __restrict__ gs, const int* __restrict__ adj,
                             const int* __restrict__ offs, const int* __restrict__ deg,
                             const float* __restrict__ dinv, const int* __restrict__ batch,
                             float* __restrict__ poolsum, int n) {
    int wave = threadIdx.x >> 6;
    int lane = threadIdx.x & 63;
    int v0 = blockIdx.x * 8 + wave * 2;
    int v1 = v0 + 1;
    if (v0 >= n) return;
    bool has1 = (v1 < n);
    float2 A0 = make_float2(0.f, 0.f), A1 = A0, A2 = A0, A3 = A0;
    float2 B0 = A0, B1 = A0, B2 = A0, B3 = A0;
    acc_h2(ROWP(gs, v0)[lane], A0);
    int s0 = offs[v0], d0 = deg[v0];
    int s1 = 0, d1 = 0;
    if (has1) {
        acc_h2(ROWP(gs, v1)[lane], B0);
        s1 = offs[v1]; d1 = deg[v1];
    }
    int i0 = 0, i1 = 0;
    JOINT_PHASE(gs)
    TAIL_LADDER(gs, s0, i0, d0, A0, A1, A2, A3)
    if (has1) { TAIL_LADDER(gs, s1, i1, d1, B0, B1, B2, B3) }

    {
        float accx = (A0.x + A1.x) + (A2.x + A3.x);
        float accy = (A0.y + A1.y) + (A2.y + A3.y);
        float dv = dinv[v0];
        float* p = poolsum + (size_t)batch[v0] * 128;
        atomicAdd(&p[lane * 2 + 0], accx * dv);
        atomicAdd(&p[lane * 2 + 1], accy * dv);
    }
    if (has1) {
        float accx = (B0.x + B1.x) + (B2.x + B3.x);
        float accy = (B0.y + B1.y) + (B2.y + B3.y);
        float dv = dinv[v1];
        float* p = poolsum + (size_t)batch[v1] * 128;
        atomicAdd(&p[lane * 2 + 0], accx * dv);
        atomicAdd(&p[lane * 2 + 1], accy * dv);
    }
}

// ---- head: emb = (pool/cnt) @ W2 + b2 ; logits = emb @ Wg + bg ----
__global__ void head(const float* __restrict__ poolsum, const int* __restrict__ cnt,
                     const float* __restrict__ W2, const float* __restrict__ b2,
                     const float* __restrict__ Wg, const float* __restrict__ bg,
                     float* __restrict__ out, int G) {
    __shared__ float pm[128];
    __shared__ float emb[256];
    int g = blockIdx.x, t = threadIdx.x;
    float inv = 1.f / fmaxf((float)cnt[g], 1.f);
    if (t < 128) pm[t] = poolsum[(size_t)g * 128 + t] * inv;
    __syncthreads();
    float acc = b2[t];
    for (int k = 0; k < 128; ++k) acc += pm[k] * W2[k * 256 + t];
    out[(size_t)g * 256 + t] = acc;
    emb[t] = acc;
    __syncthreads();
    if (t < 16) {
        float a = bg[t];
        for (int j = 0; j < 256; ++j) a += emb[j] * Wg[j * 16 + t];
        out[(size_t)G * 256 + g * 16 + t] = a;
    }
}

extern "C" void kernel_launch(void* const* d_in, const int* in_sizes, int n_in,
                              void* d_out, int out_size, void* d_ws, size_t ws_size,
                              hipStream_t stream) {
    const float* x     = (const float*)d_in[0];
    const int*   ei    = (const int*)d_in[1];
    const int*   batch = (const int*)d_in[2];
    const float* W1    = (const float*)d_in[4];
    const float* b1    = (const float*)d_in[5];
    const float* W2    = (const float*)d_in[6];
    const float* b2    = (const float*)d_in[7];
    const float* Wg    = (const float*)d_in[8];
    const float* bg    = (const float*)d_in[9];
    float* out = (float*)d_out;

    int n = in_sizes[0] / 128;
    int E = in_sizes[1] / 2;
    int G = out_size / (256 + 16);

    char* ws = (char*)d_ws;
    auto alloc = [&](size_t bytes) {
        char* p = ws;
        ws += (bytes + 255) & ~(size_t)255;
        return p;
    };
    int*    deg     = (int*)alloc((size_t)n * 4);
    float*  dinv    = (float*)alloc((size_t)n * 4);
    int*    offs    = (int*)alloc((size_t)n * 4);
    int*    cursor  = (int*)alloc((size_t)n * 4);
    int*    adj     = (int*)alloc((size_t)E * 4);
    int*    bsums   = (int*)alloc(256 * 4);
    int*    cnt     = (int*)alloc((size_t)G * 4);
    float*  poolsum = (float*)alloc((size_t)G * 128 * 4);
    __half* hs1     = (__half*)alloc((size_t)n * 128 * 2);
    __half* gs1     = (__half*)alloc((size_t)n * 128 * 2);

    hipMemsetAsync(deg, 0, (size_t)n * 4, stream);
    hipMemsetAsync(cursor, 0, (size_t)n * 4, stream);
    hipMemsetAsync(cnt, 0, (size_t)G * 4, stream);
    hipMemsetAsync(poolsum, 0, (size_t)G * 128 * 4, stream);

    count_deg<<<(E + TPB - 1) / TPB, TPB, 0, stream>>>(ei, E, deg);
    dinv_cnt<<<(n + TPB - 1) / TPB, TPB, 0, stream>>>(deg, dinv, n, batch, cnt);

    int nsb = (n + SCAN_EPB - 1) / SCAN_EPB;
    scan1<<<nsb, TPB, 0, stream>>>(deg, n, offs, bsums);
    scan2<<<1, 64, 0, stream>>>(bsums, nsb);
    scan3<<<(n + TPB - 1) / TPB, TPB, 0, stream>>>(offs, n, bsums);
    build_csr<<<(E + TPB - 1) / TPB, TPB, 0, stream>>>(ei, E, offs, cursor, adj);

    gemm1<<<(n + BM - 1) / BM, 256, 0, stream>>>(x, W1, dinv, hs1, n);
    gather1<<<(n + 7) / 8, 256, 0, stream>>>(hs1, adj, offs, deg, dinv, b1, gs1, n);
    gather2_pool<<<(n + 7) / 8, 256, 0, stream>>>(gs1, adj, offs, deg, dinv, batch, poolsum, n);
    head<<<G, 256, 0, stream>>>(poolsum, cnt, W2, b2, Wg, bg, out, G);
}

// Round 7
// 477.373 us; speedup vs baseline: 1.5122x; 1.1017x over previous
//
#include <hip/hip_runtime.h>
#include <hip/hip_fp16.h>

// ---------------------------------------------------------------------------
// ContrastiveGNN: 2-layer GCN + global mean pool + linear head.
//
//   hs1[v]   = (x[v] @ W1) * dinv[v]            (MFMA f16 GEMM, f32 acc, f16 out)
//   g1[v]    = relu(dinv[v]*(hs1[v] + sum_{u->v} hs1[u]) + b1)
//   gs1[v]   = g1[v] * dinv[v]                  (gather1, f32 math, f16 store)
//   a2[v]    = dinv[v]*(gs1[v] + sum_{u->v} gs1[u])
//   pool[g]  = mean_{v in g} a2[v]              (gather2, fused atomic pool)
//   emb      = pool @ W2 + b2 ; logits = emb @ Wg + bg   (tiny head)
//
// Gathers: 1 wave/node (r6's 2-node pairing reverted: it halved wave count,
// conserving total MLP -> neutral).  Software-pipelined: batch t+1 indices
// (scalar loads via readfirstlane'd base) and rows issued BEFORE consuming
// batch t's rows -> row latency hidden behind row latency, not stacked.
// Lane mapping (VERIFIED r4/r5): lane holds features [2*lane, 2*lane+1].
// DO NOT reintroduce the half-wave + __shfl restructure (rounds 2/3).
// ---------------------------------------------------------------------------

#define TPB 256

typedef _Float16 half8 __attribute__((ext_vector_type(8)));
typedef float floatx4 __attribute__((ext_vector_type(4)));

__global__ void count_deg(const int* __restrict__ ei, int E, int* __restrict__ deg) {
    int e = blockIdx.x * blockDim.x + threadIdx.x;
    if (e < E) atomicAdd(&deg[ei[E + e]], 1);  // dst = edge_index[1][e]
}

__global__ void dinv_cnt(const int* __restrict__ deg, float* __restrict__ dinv, int n,
                         const int* __restrict__ batch, int* __restrict__ cnt) {
    int v = blockIdx.x * blockDim.x + threadIdx.x;
    if (v < n) {
        dinv[v] = rsqrtf((float)(deg[v] + 1));   // +1 = self loop
        atomicAdd(&cnt[batch[v]], 1);
    }
}

// ---- exclusive scan of deg -> offs ----
#define SCAN_EPT 8
#define SCAN_EPB (TPB * SCAN_EPT)   // 2048

__global__ void scan1(const int* __restrict__ deg, int n,
                      int* __restrict__ offs, int* __restrict__ bsums) {
    __shared__ int s[TPB];
    int t = threadIdx.x;
    int base = blockIdx.x * SCAN_EPB + t * SCAN_EPT;
    int vals[SCAN_EPT];
    int tot = 0;
#pragma unroll
    for (int i = 0; i < SCAN_EPT; ++i) {
        int idx = base + i;
        int v = (idx < n) ? deg[idx] : 0;
        vals[i] = tot;
        tot += v;
    }
    s[t] = tot;
    __syncthreads();
    for (int off = 1; off < TPB; off <<= 1) {
        int v = (t >= off) ? s[t - off] : 0;
        __syncthreads();
        s[t] += v;
        __syncthreads();
    }
    int excl = s[t] - tot;
#pragma unroll
    for (int i = 0; i < SCAN_EPT; ++i) {
        int idx = base + i;
        if (idx < n) offs[idx] = excl + vals[i];
    }
    if (t == TPB - 1) bsums[blockIdx.x] = s[t];
}

__global__ void scan2(int* __restrict__ bsums, int nb) {
    if (threadIdx.x == 0 && blockIdx.x == 0) {
        int run = 0;
        for (int i = 0; i < nb; ++i) { int v = bsums[i]; bsums[i] = run; run += v; }
    }
}

__global__ void scan3(int* __restrict__ offs, int n, const int* __restrict__ bsums) {
    int i = blockIdx.x * blockDim.x + threadIdx.x;
    if (i < n) offs[i] += bsums[i / SCAN_EPB];
}

__global__ void build_csr(const int* __restrict__ ei, int E, const int* __restrict__ offs,
                          int* __restrict__ cursor, int* __restrict__ adj) {
    int e = blockIdx.x * blockDim.x + threadIdx.x;
    if (e < E) {
        int s = ei[e], d = ei[E + e];
        int pos = offs[d] + atomicAdd(&cursor[d], 1);
        adj[pos] = s;
    }
}

// ---- prep: Wt[c][k] = f16(W1[k][c])  (128x128, one-time transpose) ----
__global__ void prep_wt(const float* __restrict__ W, __half* __restrict__ Wt) {
    int t = blockIdx.x * blockDim.x + threadIdx.x;   // 16384
    int c = t & 127, k = t >> 7;                     // coalesced read of W row k
    Wt[c * 128 + k] = __float2half(W[(size_t)k * 128 + c]);
}

// ---- GEMM1 (MFMA f16): hs1 = (x @ W1) * dinv[row], f16 out ----
// block: 256 thr = 4 waves; tile 64(M) x 128(N); wave w -> cols [w*32, w*32+32)
// LDS XOR-swizzle byte ^= (row&7)<<4 kills the row-major-D128 bank conflict.
__global__ __launch_bounds__(256) void gemm1_mfma(const float* __restrict__ X,
                                                  const __half* __restrict__ Wt,
                                                  const float* __restrict__ dinv,
                                                  __half* __restrict__ out, int n) {
    __shared__ __align__(16) unsigned char As[64 * 128 * 2];    // f16, swizzled rows
    __shared__ __align__(16) unsigned char Bs[128 * 128 * 2];   // Bt[c][k] f16, swizzled
    int t = threadIdx.x;
    int wid = t >> 6, lane = t & 63;
    int qw = lane >> 4, lr = lane & 15;
    int rowBase = blockIdx.x * 64;

    // stage A: X (f32) -> f16, 64 rows x 128 cols, 1024 16B chunks
#pragma unroll
    for (int c = 0; c < 4; ++c) {
        int id = c * 256 + t;
        int r = id >> 4, kc = id & 15;
        int gr = rowBase + r;
        float4 x0, x1;
        if (gr < n) {
            const float4* src = (const float4*)(X + (size_t)gr * 128 + kc * 8);
            x0 = src[0]; x1 = src[1];
        } else {
            x0 = make_float4(0.f, 0.f, 0.f, 0.f); x1 = x0;
        }
        __half2 h0 = __floats2half2_rn(x0.x, x0.y);
        __half2 h1 = __floats2half2_rn(x0.z, x0.w);
        __half2 h2 = __floats2half2_rn(x1.x, x1.y);
        __half2 h3 = __floats2half2_rn(x1.z, x1.w);
        uint4 w;
        w.x = *(unsigned int*)&h0; w.y = *(unsigned int*)&h1;
        w.z = *(unsigned int*)&h2; w.w = *(unsigned int*)&h3;
        int byte = (r * 256 + kc * 16) ^ ((r & 7) << 4);
        *(uint4*)(As + byte) = w;
    }
    // stage B: Wt (f16) 128x128, 2048 16B chunks
#pragma unroll
    for (int c = 0; c < 8; ++c) {
        int id = c * 256 + t;
        int cr = id >> 4, kc = id & 15;
        uint4 w = *(const uint4*)(Wt + (size_t)cr * 128 + kc * 8);
        int byte = (cr * 256 + kc * 16) ^ ((cr & 7) << 4);
        *(uint4*)(Bs + byte) = w;
    }
    __syncthreads();

    floatx4 acc[4][2] = {};
#pragma unroll
    for (int ks = 0; ks < 4; ++ks) {
        int kb = ks * 32 + qw * 8;            // f16 elements kb..kb+7 per lane
        half8 a[4], b[2];
#pragma unroll
        for (int m = 0; m < 4; ++m) {
            int row = m * 16 + lr;
            int byte = (row * 256 + kb * 2) ^ ((row & 7) << 4);
            a[m] = *(const half8*)(As + byte);
        }
#pragma unroll
        for (int nn = 0; nn < 2; ++nn) {
            int col = wid * 32 + nn * 16 + lr;
            int byte = (col * 256 + kb * 2) ^ ((col & 7) << 4);
            b[nn] = *(const half8*)(Bs + byte);
        }
#pragma unroll
        for (int m = 0; m < 4; ++m)
#pragma unroll
            for (int nn = 0; nn < 2; ++nn)
                acc[m][nn] = __builtin_amdgcn_mfma_f32_16x16x32_f16(a[m], b[nn], acc[m][nn], 0, 0, 0);
    }

    // C/D layout (verified m89): within 16x16 tile, col = lane&15, row = (lane>>4)*4 + reg
#pragma unroll
    for (int m = 0; m < 4; ++m) {
#pragma unroll
        for (int q = 0; q < 4; ++q) {
            int gr = rowBase + m * 16 + qw * 4 + q;
            if (gr < n) {
                float dv = dinv[gr];
#pragma unroll
                for (int nn = 0; nn < 2; ++nn) {
                    int col = wid * 32 + nn * 16 + lr;
                    out[(size_t)gr * 128 + col] = __float2half(acc[m][nn][q] * dv);
                }
            }
        }
    }
}

// lane holds features [2*lane, 2*lane+1]: one half2 (4B) per lane, 256B row.
__device__ __forceinline__ void acc_h2(unsigned int rv, float2& a) {
    float2 f = __half22float2(*(__half2*)&rv);
    a.x += f.x; a.y += f.y;
}
#define ROWP(buf, u) ((const unsigned int*)((buf) + (size_t)(u) * 128))

// Software-pipelined neighbor sum: consumes all d neighbors into a0..a3.
// Batch t+1's indices + rows are issued before batch t's rows are consumed.
#define PIPE_GATHER(buf)                                                        \
    int nb = d >> 3;                                                            \
    int i = nb << 3;                                                            \
    if (nb > 0) {                                                               \
        int u0 = adj[start+0], u1 = adj[start+1], u2 = adj[start+2],            \
            u3 = adj[start+3], u4 = adj[start+4], u5 = adj[start+5],            \
            u6 = adj[start+6], u7 = adj[start+7];                               \
        unsigned c0 = ROWP(buf,u0)[lane], c1 = ROWP(buf,u1)[lane];              \
        unsigned c2 = ROWP(buf,u2)[lane], c3 = ROWP(buf,u3)[lane];              \
        unsigned c4 = ROWP(buf,u4)[lane], c5 = ROWP(buf,u5)[lane];              \
        unsigned c6 = ROWP(buf,u6)[lane], c7 = ROWP(buf,u7)[lane];              \
        for (int b = 1; b < nb; ++b) {                                          \
            int bs = start + (b << 3);                                          \
            int t0 = adj[bs+0], t1 = adj[bs+1], t2 = adj[bs+2], t3 = adj[bs+3]; \
            int t4 = adj[bs+4], t5 = adj[bs+5], t6 = adj[bs+6], t7 = adj[bs+7]; \
            unsigned n0 = ROWP(buf,t0)[lane], n1 = ROWP(buf,t1)[lane];          \
            unsigned n2 = ROWP(buf,t2)[lane], n3 = ROWP(buf,t3)[lane];          \
            unsigned n4 = ROWP(buf,t4)[lane], n5 = ROWP(buf,t5)[lane];          \
            unsigned n6 = ROWP(buf,t6)[lane], n7 = ROWP(buf,t7)[lane];          \
            acc_h2(c0, a0); acc_h2(c1, a1); acc_h2(c2, a2); acc_h2(c3, a3);     \
            acc_h2(c4, a0); acc_h2(c5, a1); acc_h2(c6, a2); acc_h2(c7, a3);     \
            c0 = n0; c1 = n1; c2 = n2; c3 = n3;                                 \
            c4 = n4; c5 = n5; c6 = n6; c7 = n7;                                 \
        }                                                                       \
        acc_h2(c0, a0); acc_h2(c1, a1); acc_h2(c2, a2); acc_h2(c3, a3);         \
        acc_h2(c4, a0); acc_h2(c5, a1); acc_h2(c6, a2); acc_h2(c7, a3);         \
    }                                                                           \
    for (; i + 3 < d; i += 4) {                                                 \
        int u0 = adj[start+i+0], u1 = adj[start+i+1];                           \
        int u2 = adj[start+i+2], u3 = adj[start+i+3];                           \
        unsigned r0 = ROWP(buf,u0)[lane], r1 = ROWP(buf,u1)[lane];              \
        unsigned r2 = ROWP(buf,u2)[lane], r3 = ROWP(buf,u3)[lane];              \
        acc_h2(r0, a0); acc_h2(r1, a1); acc_h2(r2, a2); acc_h2(r3, a3);         \
    }                                                                           \
    for (; i < d; ++i) acc_h2(ROWP(buf, adj[start + i])[lane], a0);

// ---- gather1: g1 = relu(dinv*(self+neighbors)+b1); store gs1 = g1*dinv ----
__global__ void gather1(const __half* __restrict__ hs, const int* __restrict__ adj,
                        const int* __restrict__ offs, const int* __restrict__ deg,
                        const float* __restrict__ dinv, const float* __restrict__ b1,
                        __half* __restrict__ gs, int n) {
    int wave = threadIdx.x >> 6;
    int lane = threadIdx.x & 63;
    int v = blockIdx.x * 4 + wave;
    if (v >= n) return;
    float2 a0 = make_float2(0.f, 0.f), a1 = a0, a2 = a0, a3 = a0;
    acc_h2(ROWP(hs, v)[lane], a0);                   // self loop
    int start = __builtin_amdgcn_readfirstlane(offs[v]);
    int d     = __builtin_amdgcn_readfirstlane(deg[v]);
    PIPE_GATHER(hs)
    float accx = (a0.x + a1.x) + (a2.x + a3.x);
    float accy = (a0.y + a1.y) + (a2.y + a3.y);
    float dv = dinv[v];
    float2 bb = ((const float2*)b1)[lane];
    float g0 = fmaxf(accx * dv + bb.x, 0.f) * dv;
    float g1 = fmaxf(accy * dv + bb.y, 0.f) * dv;
    __half2 h = __floats2half2_rn(g0, g1);
    ((unsigned int*)(gs + (size_t)v * 128))[lane] = *(unsigned int*)&h;
}

// ---- gather2 + fused atomic mean-pool accumulate ----
__global__ void gather2_pool(const __half* __restrict__ gs, const int* __restrict__ adj,
                             const int* __restrict__ offs, const int* __restrict__ deg,
                             const float* __restrict__ dinv, const int* __restrict__ batch,
                             float* __restrict__ poolsum, int n) {
    int wave = threadIdx.x >> 6;
    int lane = threadIdx.x & 63;
    int v = blockIdx.x * 4 + wave;
    if (v >= n) return;
    float2 a0 = make_float2(0.f, 0.f), a1 = a0, a2 = a0, a3 = a0;
    acc_h2(ROWP(gs, v)[lane], a0);
    int start = __builtin_amdgcn_readfirstlane(offs[v]);
    int d     = __builtin_amdgcn_readfirstlane(deg[v]);
    PIPE_GATHER(gs)
    float accx = (a0.x + a1.x) + (a2.x + a3.x);
    float accy = (a0.y + a1.y) + (a2.y + a3.y);
    float dv = dinv[v];
    float* p = poolsum + (size_t)batch[v] * 128;
    atomicAdd(&p[lane * 2 + 0], accx * dv);
    atomicAdd(&p[lane * 2 + 1], accy * dv);
}

// ---- head: emb = (pool/cnt) @ W2 + b2 ; logits = emb @ Wg + bg ----
__global__ void head(const float* __restrict__ poolsum, const int* __restrict__ cnt,
                     const float* __restrict__ W2, const float* __restrict__ b2,
                     const float* __restrict__ Wg, const float* __restrict__ bg,
                     float* __restrict__ out, int G) {
    __shared__ float pm[128];
    __shared__ float emb[256];
    int g = blockIdx.x, t = threadIdx.x;
    float inv = 1.f / fmaxf((float)cnt[g], 1.f);
    if (t < 128) pm[t] = poolsum[(size_t)g * 128 + t] * inv;
    __syncthreads();
    float acc = b2[t];
    for (int k = 0; k < 128; ++k) acc += pm[k] * W2[k * 256 + t];
    out[(size_t)g * 256 + t] = acc;
    emb[t] = acc;
    __syncthreads();
    if (t < 16) {
        float a = bg[t];
        for (int j = 0; j < 256; ++j) a += emb[j] * Wg[j * 16 + t];
        out[(size_t)G * 256 + g * 16 + t] = a;
    }
}

extern "C" void kernel_launch(void* const* d_in, const int* in_sizes, int n_in,
                              void* d_out, int out_size, void* d_ws, size_t ws_size,
                              hipStream_t stream) {
    const float* x     = (const float*)d_in[0];
    const int*   ei    = (const int*)d_in[1];
    const int*   batch = (const int*)d_in[2];
    const float* W1    = (const float*)d_in[4];
    const float* b1    = (const float*)d_in[5];
    const float* W2    = (const float*)d_in[6];
    const float* b2    = (const float*)d_in[7];
    const float* Wg    = (const float*)d_in[8];
    const float* bg    = (const float*)d_in[9];
    float* out = (float*)d_out;

    int n = in_sizes[0] / 128;
    int E = in_sizes[1] / 2;
    int G = out_size / (256 + 16);

    char* ws = (char*)d_ws;
    auto alloc = [&](size_t bytes) {
        char* p = ws;
        ws += (bytes + 255) & ~(size_t)255;
        return p;
    };
    int*    deg     = (int*)alloc((size_t)n * 4);
    float*  dinv    = (float*)alloc((size_t)n * 4);
    int*    offs    = (int*)alloc((size_t)n * 4);
    int*    cursor  = (int*)alloc((size_t)n * 4);
    int*    adj     = (int*)alloc((size_t)E * 4);
    int*    bsums   = (int*)alloc(256 * 4);
    int*    cnt     = (int*)alloc((size_t)G * 4);
    float*  poolsum = (float*)alloc((size_t)G * 128 * 4);
    __half* Wt      = (__half*)alloc(128 * 128 * 2);
    __half* hs1     = (__half*)alloc((size_t)n * 128 * 2);
    __half* gs1     = (__half*)alloc((size_t)n * 128 * 2);

    hipMemsetAsync(deg, 0, (size_t)n * 4, stream);
    hipMemsetAsync(cursor, 0, (size_t)n * 4, stream);
    hipMemsetAsync(cnt, 0, (size_t)G * 4, stream);
    hipMemsetAsync(poolsum, 0, (size_t)G * 128 * 4, stream);

    count_deg<<<(E + TPB - 1) / TPB, TPB, 0, stream>>>(ei, E, deg);
    dinv_cnt<<<(n + TPB - 1) / TPB, TPB, 0, stream>>>(deg, dinv, n, batch, cnt);

    int nsb = (n + SCAN_EPB - 1) / SCAN_EPB;
    scan1<<<nsb, TPB, 0, stream>>>(deg, n, offs, bsums);
    scan2<<<1, 64, 0, stream>>>(bsums, nsb);
    scan3<<<(n + TPB - 1) / TPB, TPB, 0, stream>>>(offs, n, bsums);
    build_csr<<<(E + TPB - 1) / TPB, TPB, 0, stream>>>(ei, E, offs, cursor, adj);

    prep_wt<<<64, TPB, 0, stream>>>(W1, Wt);
    gemm1_mfma<<<(n + 63) / 64, 256, 0, stream>>>(x, Wt, dinv, hs1, n);
    gather1<<<(n + 3) / 4, 256, 0, stream>>>(hs1, adj, offs, deg, dinv, b1, gs1, n);
    gather2_pool<<<(n + 3) / 4, 256, 0, stream>>>(gs1, adj, offs, deg, dinv, batch, poolsum, n);
    head<<<G, 256, 0, stream>>>(poolsum, cnt, W2, b2, Wg, bg, out, G);
}

// Round 8
// 362.173 us; speedup vs baseline: 1.9932x; 1.3181x over previous
//
#include <hip/hip_runtime.h>
#include <hip/hip_fp16.h>

// ---------------------------------------------------------------------------
// ContrastiveGNN: 2-layer GCN + global mean pool + linear head.
//
//   hs1[v]   = (x[v] @ W1) * dinv[v]            (MFMA f16 GEMM, f32 acc, f16 out)
//   g1[v]    = relu(dinv[v]*(hs1[v] + sum_{u->v} hs1[u]) + b1)
//   gs1[v]   = g1[v] * dinv[v]                  (gather1, f32 math, f16 store)
//   a2[v]    = dinv[v]*(gs1[v] + sum_{u->v} gs1[u])
//   pool[g]  = mean_{v in g} a2[v]              (gather2, fused atomic pool)
//   emb      = pool @ W2 + b2 ; logits = emb @ Wg + bg   (tiny head)
//
// CSR build (r8 rewrite): the old atomic-scatter build_csr wrote 4B at random
// positions over 6.4MB from all XCDs -> 107MB writeback amp + 1.6M global
// atomics = 125us.  New 3-phase bucket sort: every global write lands in a
// BLOCK-PRIVATE contiguous region (chunk region in K1, bucket adj region in
// K3) so cache lines are written by one XCD and written back once.  K3 also
// produces offs/deg/dinv/cnt, eliminating count_deg + 3 scan kernels.
//
// Gathers (VERIFIED r4/r5/r7): 1 wave/node, lane holds features
// [2*lane, 2*lane+1] (half2), software-pipelined 8-deep.
// DO NOT reintroduce the half-wave + __shfl restructure (rounds 2/3).
// ---------------------------------------------------------------------------

#define TPB 256
#define CHUNK 4096          // edges per K1 block
#define MAXB 512            // max buckets AND max chunks (LDS arrays)

typedef _Float16 half8 __attribute__((ext_vector_type(8)));
typedef float floatx4 __attribute__((ext_vector_type(4)));

// exclusive scan of a[0..512) in LDS (caller pads with zeros), 256 threads.
// part[255] holds the total after the call.
__device__ __forceinline__ void exscan512(int* a, int* part, int t) {
    int x0 = a[2 * t], x1 = a[2 * t + 1];
    part[t] = x0 + x1;
    __syncthreads();
    for (int off = 1; off < 256; off <<= 1) {
        int v = (t >= off) ? part[t - off] : 0;
        __syncthreads();
        part[t] += v;
        __syncthreads();
    }
    int base = (t > 0) ? part[t - 1] : 0;
    a[2 * t] = base;
    a[2 * t + 1] = base + x0;
    __syncthreads();
}

// ---- K1: per-chunk bucket sort of edges (bucket = dst>>8) ----
__global__ __launch_bounds__(256) void k1_bucket(const int* __restrict__ ei, int E,
                                                 int B, int nchunks,
                                                 uint2* __restrict__ sorted,
                                                 int* __restrict__ histT,
                                                 int* __restrict__ sstartT,
                                                 int* __restrict__ bucketTot) {
    __shared__ int hcnt[MAXB], hoff[MAXB], hcur[MAXB], part[256];
    int c = blockIdx.x, t = threadIdx.x;
    int e0 = c * CHUNK;
    int m = E - e0; if (m > CHUNK) m = CHUNK;
    for (int i = t; i < MAXB; i += 256) { hcnt[i] = 0; hcur[i] = 0; }
    __syncthreads();
    for (int i = t; i < m; i += 256)
        atomicAdd(&hcnt[ei[E + e0 + i] >> 8], 1);
    __syncthreads();
    for (int i = t; i < MAXB; i += 256) hoff[i] = hcnt[i];
    __syncthreads();
    exscan512(hoff, part, t);
    for (int i = t; i < B; i += 256) {
        histT[(size_t)i * nchunks + c]   = hcnt[i];
        sstartT[(size_t)i * nchunks + c] = e0 + hoff[i];
        if (hcnt[i] > 0) atomicAdd(&bucketTot[i], hcnt[i]);
    }
    __syncthreads();
    // scatter into block-private region [e0, e0+m)
    for (int i = t; i < m; i += 256) {
        int src = ei[e0 + i], dst = ei[E + e0 + i];
        int b = dst >> 8;
        int pos = e0 + hoff[b] + atomicAdd(&hcur[b], 1);
        sorted[pos] = make_uint2((unsigned)src, (unsigned)dst);
    }
}

// ---- K2: exclusive scan of bucket totals -> adj base per bucket ----
__global__ void k2_scanB(const int* __restrict__ bucketTot, int B,
                         int* __restrict__ bucketBase) {
    __shared__ int a[MAXB], part[256];
    int t = threadIdx.x;
    a[t]       = (t < B) ? bucketTot[t] : 0;
    a[t + 256] = (t + 256 < B) ? bucketTot[t + 256] : 0;
    __syncthreads();
    exscan512(a, part, t);
    if (t < B) bucketBase[t] = a[t];
    if (t + 256 < B) bucketBase[t + 256] = a[t + 256];
    if (t == 255) bucketBase[B] = part[255];
}

// ---- K3: per-bucket scatter -> adj (private contiguous region) + offs/deg/dinv/cnt ----
__global__ __launch_bounds__(256) void k3_scatter(const uint2* __restrict__ sorted,
                                                  const int* __restrict__ histT,
                                                  const int* __restrict__ sstartT,
                                                  const int* __restrict__ bucketBase,
                                                  const int* __restrict__ batch,
                                                  int* __restrict__ adj,
                                                  int* __restrict__ offs,
                                                  int* __restrict__ deg,
                                                  float* __restrict__ dinv,
                                                  int* __restrict__ cnt,
                                                  int n, int nchunks) {
    __shared__ int sliceS[MAXB], sliceOff[MAXB], part[256];
    __shared__ int ncnt[256], noff[512], ncur[256];
    int b = blockIdx.x, t = threadIdx.x;
    int vb = b << 8;
    for (int i = t; i < MAXB; i += 256) {
        sliceOff[i] = (i < nchunks) ? histT[(size_t)b * nchunks + i] : 0;
        sliceS[i]   = (i < nchunks) ? sstartT[(size_t)b * nchunks + i] : 0;
    }
    ncnt[t] = 0;
    __syncthreads();
    exscan512(sliceOff, part, t);
    int T = part[255];
    // pass 1: per-node degree count
    for (int i = t; i < T; i += 256) {
        int lo = 0, hi = nchunks - 1;
        while (lo < hi) {                      // last c with sliceOff[c] <= i
            int mid = (lo + hi + 1) >> 1;
            if (sliceOff[mid] <= i) lo = mid; else hi = mid - 1;
        }
        uint2 e = sorted[sliceS[lo] + (i - sliceOff[lo])];
        atomicAdd(&ncnt[(int)e.y - vb], 1);
    }
    __syncthreads();
    for (int i = t; i < 512; i += 256) noff[i] = (i < 256) ? ncnt[i] : 0;
    __syncthreads();
    exscan512(noff, part, t);
    int base = bucketBase[b];
    int v = vb + t;
    if (v < n) {
        int dg = ncnt[t];
        offs[v] = base + noff[t];
        deg[v]  = dg;
        dinv[v] = rsqrtf((float)(dg + 1));     // +1 = self loop
        atomicAdd(&cnt[batch[v]], 1);
    }
    ncur[t] = 0;
    __syncthreads();
    // pass 2: scatter src into private adj region [bucketBase[b], bucketBase[b+1])
    for (int i = t; i < T; i += 256) {
        int lo = 0, hi = nchunks - 1;
        while (lo < hi) {
            int mid = (lo + hi + 1) >> 1;
            if (sliceOff[mid] <= i) lo = mid; else hi = mid - 1;
        }
        uint2 e = sorted[sliceS[lo] + (i - sliceOff[lo])];
        int r = (int)e.y - vb;
        int pos = base + noff[r] + atomicAdd(&ncur[r], 1);
        adj[pos] = (int)e.x;
    }
}

// ---- prep: Wt[c][k] = f16(W1[k][c])  (128x128, one-time transpose) ----
__global__ void prep_wt(const float* __restrict__ W, __half* __restrict__ Wt) {
    int t = blockIdx.x * blockDim.x + threadIdx.x;   // 16384
    int c = t & 127, k = t >> 7;
    Wt[c * 128 + k] = __float2half(W[(size_t)k * 128 + c]);
}

// ---- GEMM1 (MFMA f16): hs1 = (x @ W1) * dinv[row], f16 out ----
__global__ __launch_bounds__(256) void gemm1_mfma(const float* __restrict__ X,
                                                  const __half* __restrict__ Wt,
                                                  const float* __restrict__ dinv,
                                                  __half* __restrict__ out, int n) {
    __shared__ __align__(16) unsigned char As[64 * 128 * 2];
    __shared__ __align__(16) unsigned char Bs[128 * 128 * 2];
    int t = threadIdx.x;
    int wid = t >> 6, lane = t & 63;
    int qw = lane >> 4, lr = lane & 15;
    int rowBase = blockIdx.x * 64;

#pragma unroll
    for (int c = 0; c < 4; ++c) {
        int id = c * 256 + t;
        int r = id >> 4, kc = id & 15;
        int gr = rowBase + r;
        float4 x0, x1;
        if (gr < n) {
            const float4* src = (const float4*)(X + (size_t)gr * 128 + kc * 8);
            x0 = src[0]; x1 = src[1];
        } else {
            x0 = make_float4(0.f, 0.f, 0.f, 0.f); x1 = x0;
        }
        __half2 h0 = __floats2half2_rn(x0.x, x0.y);
        __half2 h1 = __floats2half2_rn(x0.z, x0.w);
        __half2 h2 = __floats2half2_rn(x1.x, x1.y);
        __half2 h3 = __floats2half2_rn(x1.z, x1.w);
        uint4 w;
        w.x = *(unsigned int*)&h0; w.y = *(unsigned int*)&h1;
        w.z = *(unsigned int*)&h2; w.w = *(unsigned int*)&h3;
        int byte = (r * 256 + kc * 16) ^ ((r & 7) << 4);
        *(uint4*)(As + byte) = w;
    }
#pragma unroll
    for (int c = 0; c < 8; ++c) {
        int id = c * 256 + t;
        int cr = id >> 4, kc = id & 15;
        uint4 w = *(const uint4*)(Wt + (size_t)cr * 128 + kc * 8);
        int byte = (cr * 256 + kc * 16) ^ ((cr & 7) << 4);
        *(uint4*)(Bs + byte) = w;
    }
    __syncthreads();

    floatx4 acc[4][2] = {};
#pragma unroll
    for (int ks = 0; ks < 4; ++ks) {
        int kb = ks * 32 + qw * 8;
        half8 a[4], b[2];
#pragma unroll
        for (int m = 0; m < 4; ++m) {
            int row = m * 16 + lr;
            int byte = (row * 256 + kb * 2) ^ ((row & 7) << 4);
            a[m] = *(const half8*)(As + byte);
        }
#pragma unroll
        for (int nn = 0; nn < 2; ++nn) {
            int col = wid * 32 + nn * 16 + lr;
            int byte = (col * 256 + kb * 2) ^ ((col & 7) << 4);
            b[nn] = *(const half8*)(Bs + byte);
        }
#pragma unroll
        for (int m = 0; m < 4; ++m)
#pragma unroll
            for (int nn = 0; nn < 2; ++nn)
                acc[m][nn] = __builtin_amdgcn_mfma_f32_16x16x32_f16(a[m], b[nn], acc[m][nn], 0, 0, 0);
    }

#pragma unroll
    for (int m = 0; m < 4; ++m) {
#pragma unroll
        for (int q = 0; q < 4; ++q) {
            int gr = rowBase + m * 16 + qw * 4 + q;
            if (gr < n) {
                float dv = dinv[gr];
#pragma unroll
                for (int nn = 0; nn < 2; ++nn) {
                    int col = wid * 32 + nn * 16 + lr;
                    out[(size_t)gr * 128 + col] = __float2half(acc[m][nn][q] * dv);
                }
            }
        }
    }
}

// lane holds features [2*lane, 2*lane+1]: one half2 (4B) per lane, 256B row.
__device__ __forceinline__ void acc_h2(unsigned int rv, float2& a) {
    float2 f = __half22float2(*(__half2*)&rv);
    a.x += f.x; a.y += f.y;
}
#define ROWP(buf, u) ((const unsigned int*)((buf) + (size_t)(u) * 128))

// Software-pipelined neighbor sum (r7 verified).
#define PIPE_GATHER(buf)                                                        \
    int nb = d >> 3;                                                            \
    int i = nb << 3;                                                            \
    if (nb > 0) {                                                               \
        int u0 = adj[start+0], u1 = adj[start+1], u2 = adj[start+2],            \
            u3 = adj[start+3], u4 = adj[start+4], u5 = adj[start+5],            \
            u6 = adj[start+6], u7 = adj[start+7];                               \
        unsigned c0 = ROWP(buf,u0)[lane], c1 = ROWP(buf,u1)[lane];              \
        unsigned c2 = ROWP(buf,u2)[lane], c3 = ROWP(buf,u3)[lane];              \
        unsigned c4 = ROWP(buf,u4)[lane], c5 = ROWP(buf,u5)[lane];              \
        unsigned c6 = ROWP(buf,u6)[lane], c7 = ROWP(buf,u7)[lane];              \
        for (int b = 1; b < nb; ++b) {                                          \
            int bs = start + (b << 3);                                          \
            int t0 = adj[bs+0], t1 = adj[bs+1], t2 = adj[bs+2], t3 = adj[bs+3]; \
            int t4 = adj[bs+4], t5 = adj[bs+5], t6 = adj[bs+6], t7 = adj[bs+7]; \
            unsigned n0 = ROWP(buf,t0)[lane], n1 = ROWP(buf,t1)[lane];          \
            unsigned n2 = ROWP(buf,t2)[lane], n3 = ROWP(buf,t3)[lane];          \
            unsigned n4 = ROWP(buf,t4)[lane], n5 = ROWP(buf,t5)[lane];          \
            unsigned n6 = ROWP(buf,t6)[lane], n7 = ROWP(buf,t7)[lane];          \
            acc_h2(c0, a0); acc_h2(c1, a1); acc_h2(c2, a2); acc_h2(c3, a3);     \
            acc_h2(c4, a0); acc_h2(c5, a1); acc_h2(c6, a2); acc_h2(c7, a3);     \
            c0 = n0; c1 = n1; c2 = n2; c3 = n3;                                 \
            c4 = n4; c5 = n5; c6 = n6; c7 = n7;                                 \
        }                                                                       \
        acc_h2(c0, a0); acc_h2(c1, a1); acc_h2(c2, a2); acc_h2(c3, a3);         \
        acc_h2(c4, a0); acc_h2(c5, a1); acc_h2(c6, a2); acc_h2(c7, a3);         \
    }                                                                           \
    for (; i + 3 < d; i += 4) {                                                 \
        int u0 = adj[start+i+0], u1 = adj[start+i+1];                           \
        int u2 = adj[start+i+2], u3 = adj[start+i+3];                           \
        unsigned r0 = ROWP(buf,u0)[lane], r1 = ROWP(buf,u1)[lane];              \
        unsigned r2 = ROWP(buf,u2)[lane], r3 = ROWP(buf,u3)[lane];              \
        acc_h2(r0, a0); acc_h2(r1, a1); acc_h2(r2, a2); acc_h2(r3, a3);         \
    }                                                                           \
    for (; i < d; ++i) acc_h2(ROWP(buf, adj[start + i])[lane], a0);

// ---- gather1: g1 = relu(dinv*(self+neighbors)+b1); store gs1 = g1*dinv ----
__global__ void gather1(const __half* __restrict__ hs, const int* __restrict__ adj,
                        const int* __restrict__ offs, const int* __restrict__ deg,
                        const float* __restrict__ dinv, const float* __restrict__ b1,
                        __half* __restrict__ gs, int n) {
    int wave = threadIdx.x >> 6;
    int lane = threadIdx.x & 63;
    int v = blockIdx.x * 4 + wave;
    if (v >= n) return;
    float2 a0 = make_float2(0.f, 0.f), a1 = a0, a2 = a0, a3 = a0;
    acc_h2(ROWP(hs, v)[lane], a0);                   // self loop
    int start = __builtin_amdgcn_readfirstlane(offs[v]);
    int d     = __builtin_amdgcn_readfirstlane(deg[v]);
    PIPE_GATHER(hs)
    float accx = (a0.x + a1.x) + (a2.x + a3.x);
    float accy = (a0.y + a1.y) + (a2.y + a3.y);
    float dv = dinv[v];
    float2 bb = ((const float2*)b1)[lane];
    float g0 = fmaxf(accx * dv + bb.x, 0.f) * dv;
    float g1 = fmaxf(accy * dv + bb.y, 0.f) * dv;
    __half2 h = __floats2half2_rn(g0, g1);
    ((unsigned int*)(gs + (size_t)v * 128))[lane] = *(unsigned int*)&h;
}

// ---- gather2 + fused atomic mean-pool accumulate ----
__global__ void gather2_pool(const __half* __restrict__ gs, const int* __restrict__ adj,
                             const int* __restrict__ offs, const int* __restrict__ deg,
                             const float* __restrict__ dinv, const int* __restrict__ batch,
                             float* __restrict__ poolsum, int n) {
    int wave = threadIdx.x >> 6;
    int lane = threadIdx.x & 63;
    int v = blockIdx.x * 4 + wave;
    if (v >= n) return;
    float2 a0 = make_float2(0.f, 0.f), a1 = a0, a2 = a0, a3 = a0;
    acc_h2(ROWP(gs, v)[lane], a0);
    int start = __builtin_amdgcn_readfirstlane(offs[v]);
    int d     = __builtin_amdgcn_readfirstlane(deg[v]);
    PIPE_GATHER(gs)
    float accx = (a0.x + a1.x) + (a2.x + a3.x);
    float accy = (a0.y + a1.y) + (a2.y + a3.y);
    float dv = dinv[v];
    float* p = poolsum + (size_t)batch[v] * 128;
    atomicAdd(&p[lane * 2 + 0], accx * dv);
    atomicAdd(&p[lane * 2 + 1], accy * dv);
}

// ---- head: emb = (pool/cnt) @ W2 + b2 ; logits = emb @ Wg + bg ----
__global__ void head(const float* __restrict__ poolsum, const int* __restrict__ cnt,
                     const float* __restrict__ W2, const float* __restrict__ b2,
                     const float* __restrict__ Wg, const float* __restrict__ bg,
                     float* __restrict__ out, int G) {
    __shared__ float pm[128];
    __shared__ float emb[256];
    int g = blockIdx.x, t = threadIdx.x;
    float inv = 1.f / fmaxf((float)cnt[g], 1.f);
    if (t < 128) pm[t] = poolsum[(size_t)g * 128 + t] * inv;
    __syncthreads();
    float acc = b2[t];
    for (int k = 0; k < 128; ++k) acc += pm[k] * W2[k * 256 + t];
    out[(size_t)g * 256 + t] = acc;
    emb[t] = acc;
    __syncthreads();
    if (t < 16) {
        float a = bg[t];
        for (int j = 0; j < 256; ++j) a += emb[j] * Wg[j * 16 + t];
        out[(size_t)G * 256 + g * 16 + t] = a;
    }
}

extern "C" void kernel_launch(void* const* d_in, const int* in_sizes, int n_in,
                              void* d_out, int out_size, void* d_ws, size_t ws_size,
                              hipStream_t stream) {
    const float* x     = (const float*)d_in[0];
    const int*   ei    = (const int*)d_in[1];
    const int*   batch = (const int*)d_in[2];
    const float* W1    = (const float*)d_in[4];
    const float* b1    = (const float*)d_in[5];
    const float* W2    = (const float*)d_in[6];
    const float* b2    = (const float*)d_in[7];
    const float* Wg    = (const float*)d_in[8];
    const float* bg    = (const float*)d_in[9];
    float* out = (float*)d_out;

    int n = in_sizes[0] / 128;
    int E = in_sizes[1] / 2;
    int G = out_size / (256 + 16);
    int B = (n + 255) >> 8;                 // buckets of 256 nodes (<= 512)
    int nchunks = (E + CHUNK - 1) / CHUNK;  // <= 512

    char* ws = (char*)d_ws;
    auto alloc = [&](size_t bytes) {
        char* p = ws;
        ws += (bytes + 255) & ~(size_t)255;
        return p;
    };
    int*    deg       = (int*)alloc((size_t)n * 4);
    float*  dinv      = (float*)alloc((size_t)n * 4);
    int*    offs      = (int*)alloc((size_t)n * 4);
    int*    adj       = (int*)alloc((size_t)E * 4);
    uint2*  sorted    = (uint2*)alloc((size_t)E * 8);
    int*    histT     = (int*)alloc((size_t)B * nchunks * 4);
    int*    sstartT   = (int*)alloc((size_t)B * nchunks * 4);
    int*    bucketTot = (int*)alloc((size_t)(B + 1) * 4);
    int*    bucketBase= (int*)alloc((size_t)(B + 1) * 4);
    int*    cnt       = (int*)alloc((size_t)G * 4);
    float*  poolsum   = (float*)alloc((size_t)G * 128 * 4);
    __half* Wt        = (__half*)alloc(128 * 128 * 2);
    __half* hs1       = (__half*)alloc((size_t)n * 128 * 2);
    __half* gs1       = (__half*)alloc((size_t)n * 128 * 2);

    hipMemsetAsync(bucketTot, 0, (size_t)(B + 1) * 4, stream);
    hipMemsetAsync(cnt, 0, (size_t)G * 4, stream);
    hipMemsetAsync(poolsum, 0, (size_t)G * 128 * 4, stream);

    k1_bucket<<<nchunks, 256, 0, stream>>>(ei, E, B, nchunks, sorted, histT, sstartT, bucketTot);
    k2_scanB<<<1, 256, 0, stream>>>(bucketTot, B, bucketBase);
    k3_scatter<<<B, 256, 0, stream>>>(sorted, histT, sstartT, bucketBase, batch,
                                      adj, offs, deg, dinv, cnt, n, nchunks);

    prep_wt<<<64, TPB, 0, stream>>>(W1, Wt);
    gemm1_mfma<<<(n + 63) / 64, 256, 0, stream>>>(x, Wt, dinv, hs1, n);
    gather1<<<(n + 3) / 4, 256, 0, stream>>>(hs1, adj, offs, deg, dinv, b1, gs1, n);
    gather2_pool<<<(n + 3) / 4, 256, 0, stream>>>(gs1, adj, offs, deg, dinv, batch, poolsum, n);
    head<<<G, 256, 0, stream>>>(poolsum, cnt, W2, b2, Wg, bg, out, G);
}